// Round 10
// baseline (1624.413 us; speedup 1.0000x reference)
//
#include <hip/hip_runtime.h>
#include <math.h>

// Problem constants
#define BATCH 1024
#define NA 10
#define NEN 10
#define NALY 9
#define NAG (BATCH*NA)          // 10240
#define NEE (NAG*NEN)           // 102400
#define NAE (NAG*NALY)          // 92160
#define EPSF 1e-5f

// f64 replicated qbn-sum buffers (16 replicas), at start of ws (double units)
#define DOFF_SE1 0
#define DOFF_SE2 1024
#define DOFF_SA1 2048
#define DOFF_SA2 3072
#define DOFF_SF1 4096
#define DOFF_SF2 5120
#define DOFF_SIE1 6144
#define DOFF_SIE2 7168
#define DOFF_SIA1 8192
#define DOFF_SIA2 9216
#define DOFF_SIE3 10240
#define DOFF_SIA3 10256
#define NDOUBLES 16384

__device__ __forceinline__ double sum16vd(const double* __restrict__ S, int ch) {
    double s = 0.0;
#pragma unroll
    for (int r = 0; r < 16; ++r) s += S[r*64 + ch];
    return s;
}
__device__ __forceinline__ double sum16sd(const double* __restrict__ S) {
    double s = 0.0;
#pragma unroll
    for (int r = 0; r < 16; ++r) s += S[r];
    return s;
}
// qbn scale: s = fl32(sqrt(fl32(exact_mean) + eps))
__device__ __forceinline__ float qbn_s(const double* __restrict__ S, int ch, double invRows) {
    float m = (float)(sum16vd(S, ch)*invRows);
    return sqrtf(m + EPSF);
}
__device__ __forceinline__ void red_to_S(const double* red, double* S, int bid, int tid) {
    if (tid < 64) {
        double v = red[tid] + red[tid+64] + red[tid+128] + red[tid+192];
        atomicAdd(&S[(bid & 15)*64 + tid], v);
    }
}
// np-lattice pair mod^2: fl(fl(x0^2)+fl(x1^2)) (no FMA contraction)
__device__ __forceinline__ float pair_m2(float x0, float x1) {
    return __fadd_rn(__fmul_rn(x0,x0), __fmul_rn(x1,x1));
}

// ---- build_vec + layer1 GEMM, per pair element; f32 FMA dot, REVERSED k
//      (element-noise reroll vs R5's forward order). ----
__global__ __launch_bounds__(256) void k_build_pair(
    const float* __restrict__ feats, const float* __restrict__ own,
    const float* __restrict__ W1, float* __restrict__ X,
    double* __restrict__ S1, int nEntPerAgent)
{
    __shared__ float wlds[19*64];
    __shared__ float g[2][19];
    __shared__ float pxy[2][2];
    __shared__ double red[256];
    int tid = threadIdx.x;
    for (int i = tid; i < 19*64; i += 256) wlds[i] = W1[i];
    int l = tid >> 7, c = (tid >> 6) & 1, ch = tid & 63;
    int ent = blockIdx.x*2 + l;
    if (c == 0 && ch < 19) {
        const float* f = feats + (size_t)ent*9;
        int agent = ent / nEntPerAgent;
        float px = f[2], py = f[3];
        float pm = sqrtf(__fadd_rn(__fmul_rn(px,px), __fmul_rn(py,py)));
        float val;
        if (ch == 0) val = 1.f;
        else if (ch < 8) {
            int j = ch - 1;
            int fi = (j < 2) ? j : (j + 2);
            float o = f[fi];
            float om = sqrtf(__fmul_rn(__fmul_rn(2.0f,o),o));
            val = (pm == 0.f) ? 0.f : __fdiv_rn(om, pm);
        } else {
            float o = own[(size_t)agent*11 + (ch-8)];
            float t = __fmul_rn(o,o);
            float om = sqrtf(__fadd_rn(t,t));
            val = (pm == 0.f) ? 0.f : __fdiv_rn(om, pm);
        }
        g[l][ch] = val;
        if (ch == 0) { pxy[l][0] = px; pxy[l][1] = py; }
    }
    __syncthreads();
    float pc = pxy[l][c];
    float acc = 0.f;
#pragma unroll
    for (int k = 18; k >= 0; --k) {            // REVERSED k order
        float ev = __fmul_rn(pc, g[l][k]);
        acc = fmaf(ev, wlds[k*64+ch], acc);
    }
    X[(size_t)ent*128 + c*64 + ch] = acc;
    red[tid] = (double)acc * (double)acc;
    __syncthreads();
    red_to_S(red, S1, blockIdx.x, tid);
}

// ---- pair layer: qbn + qrelu + 64x64 GEMM (f32 FMA, REVERSED k), in place. --
__global__ __launch_bounds__(256) void k_pair_layer(
    float* __restrict__ X, const double* __restrict__ Sin, double* __restrict__ Sout,
    const float* __restrict__ W, double invRows)
{
    __shared__ float wlds[4096];
    __shared__ float ybuf[4][2][64];
    __shared__ double red[256];
    int tid = threadIdx.x;
    for (int i = tid; i < 4096; i += 256) wlds[i] = W[i];
    int grp = tid>>6, ch = tid&63;
    int row = blockIdx.x*4 + grp;
    float x0 = X[(size_t)row*128+ch], x1 = X[(size_t)row*128+64+ch];
    float s = qbn_s(Sin, ch, invRows);
    float u0 = x0/s, u1 = x1/s;
    float mod = sqrtf(pair_m2(u0,u1));
    float cf = mod / fmaxf(1.f, mod);
    ybuf[grp][0][ch] = __fmul_rn(u0,cf);
    ybuf[grp][1][ch] = __fmul_rn(u1,cf);
    __syncthreads();
    float a0 = 0.f, a1 = 0.f;
#pragma unroll
    for (int k = 63; k >= 0; --k) {            // REVERSED k order
        float w = wlds[k*64+ch];
        a0 = fmaf(ybuf[grp][0][k], w, a0);
        a1 = fmaf(ybuf[grp][1][k], w, a1);
    }
    X[(size_t)row*128+ch] = a0; X[(size_t)row*128+64+ch] = a1;
    red[tid] = (double)a0*a0 + (double)a1*a1;
    __syncthreads();
    red_to_S(red, Sout, blockIdx.x, tid);
}

// ---- Finalize: y = qrelu(qbn(x)) per pair element, in place. ----
__global__ __launch_bounds__(256) void k_finalize_pair(
    float* __restrict__ X, const double* __restrict__ S2, double invRows)
{
    int idx = blockIdx.x*256 + threadIdx.x;
    int ch = idx & 63, c = (idx>>6) & 1;
    float x  = X[idx];
    float xo = X[idx^64];
    __syncthreads();
    float s = qbn_s(S2, ch, invRows);
    float u  = x/s;
    float uo = xo/s;
    float u0 = (c==0) ? u : uo, u1 = (c==0) ? uo : u;
    float mod = sqrtf(pair_m2(u0,u1));
    float cf = mod / fmaxf(1.f, mod);
    X[idx] = __fmul_rn(u, cf);
}

// ---- Pool (argmax over 19, enemies first, strict first-max like np) + f1. ----
__global__ __launch_bounds__(256) void k_pool_f1(
    const float* __restrict__ XE, const float* __restrict__ XA,
    const float* __restrict__ Wf1, float* __restrict__ F1, double* __restrict__ Sf1)
{
    __shared__ float wlds[4096];
    __shared__ float v[4][2][64];
    __shared__ double red[256];
    int tid = threadIdx.x;
    for (int i = tid; i < 4096; i += 256) wlds[i] = Wf1[i];
    int grp = tid>>6, ch = tid&63;
    int agent = blockIdx.x*4 + grp;
    float best = -1.f, v0 = 0.f, v1 = 0.f;
    for (int e = 0; e < NEN; ++e) {
        size_t b = (size_t)(agent*NEN+e)*128;
        float x0 = XE[b+ch], x1 = XE[b+64+ch];
        float m2 = pair_m2(x0,x1);
        if (m2 > best) { best = m2; v0 = x0; v1 = x1; }
    }
    for (int l = 0; l < NALY; ++l) {
        size_t b = (size_t)(agent*NALY+l)*128;
        float x0 = XA[b+ch], x1 = XA[b+64+ch];
        float m2 = pair_m2(x0,x1);
        if (m2 > best) { best = m2; v0 = x0; v1 = x1; }
    }
    v[grp][0][ch] = v0; v[grp][1][ch] = v1;
    __syncthreads();
    float a0 = 0.f, a1 = 0.f;
#pragma unroll
    for (int k = 0; k < 64; ++k) {
        float w = wlds[k*64+ch];
        a0 = fmaf(v[grp][0][k], w, a0);
        a1 = fmaf(v[grp][1][k], w, a1);
    }
    F1[(size_t)agent*128+ch] = a0; F1[(size_t)agent*128+64+ch] = a1;
    red[tid] = (double)a0*a0 + (double)a1*a1;
    __syncthreads();
    red_to_S(red, Sf1, blockIdx.x, tid);
}

// ---- vf finalize + SFb + VT = vf @ W1top for both imp chains. ----
__global__ __launch_bounds__(256) void k_vf_vtop(
    const float* __restrict__ F1, const double* __restrict__ Sf2,
    float* __restrict__ SFb,
    const float* __restrict__ Wie1, const float* __restrict__ Wia1,
    float* __restrict__ VTie, float* __restrict__ VTia, double invRows)
{
    __shared__ float wie[4096];
    __shared__ float wia[4096];
    __shared__ float vf[4][2][64];
    int tid = threadIdx.x;
    for (int i = tid; i < 4096; i += 256) { wie[i] = Wie1[i]; wia[i] = Wia1[i]; }
    int grp = tid>>6, ch = tid&63;
    int agent = blockIdx.x*4 + grp;
    float x0 = F1[(size_t)agent*128+ch], x1 = F1[(size_t)agent*128+64+ch];
    float s = qbn_s(Sf2, ch, invRows);
    float u0 = x0/s, u1 = x1/s;
    float mod = sqrtf(pair_m2(u0,u1));
    float cf = mod / fmaxf(1.f, mod);
    float y0 = __fmul_rn(u0,cf), y1 = __fmul_rn(u1,cf);
    vf[grp][0][ch] = y0; vf[grp][1][ch] = y1;
    SFb[(size_t)agent*64+ch] = pair_m2(y0,y1);
    __syncthreads();
    float a0=0.f,a1=0.f,b0=0.f,b1=0.f;
#pragma unroll
    for (int k = 0; k < 64; ++k) {
        float f0 = vf[grp][0][k], f1 = vf[grp][1][k];
        a0 = fmaf(f0, wie[k*64+ch], a0); a1 = fmaf(f1, wie[k*64+ch], a1);
        b0 = fmaf(f0, wia[k*64+ch], b0); b1 = fmaf(f1, wia[k*64+ch], b1);
    }
    VTie[(size_t)agent*128+ch] = a0; VTie[(size_t)agent*128+64+ch] = a1;
    VTia[(size_t)agent*128+ch] = b0; VTia[(size_t)agent*128+64+ch] = b1;
}

// ---- imp layer1: XI = VT + XE @ W1bot (f32 FMA), f64 stats S1. ----
__global__ __launch_bounds__(256) void k_imp1(
    const float* __restrict__ XE, const float* __restrict__ VT,
    const float* __restrict__ W1, float* __restrict__ XI, double* __restrict__ S1)
{
    __shared__ float wlds[4096];
    __shared__ float xt[256];
    __shared__ double red[256];
    int tid = threadIdx.x;
    for (int i = tid; i < 4096; i += 256) wlds[i] = W1[4096 + i];
    int l = tid>>7, c = (tid>>6)&1, ch = tid&63;
    int ent = blockIdx.x*2 + l;
    int agent = ent / NEN;
    xt[tid] = XE[(size_t)blockIdx.x*256 + tid];
    __syncthreads();
    const float* xr = &xt[l*128 + c*64];
    float acc = VT[(size_t)agent*128 + c*64 + ch];
#pragma unroll
    for (int k = 0; k < 64; ++k) acc = fmaf(xr[k], wlds[k*64+ch], acc);
    XI[(size_t)ent*128 + c*64 + ch] = acc;
    red[tid] = (double)acc*(double)acc;
    __syncthreads();
    red_to_S(red, S1, blockIdx.x, tid);
}

// ---- imp layer3: qbn(S2)+qrelu then dot W3 -> Z, stats S3. ----
__global__ __launch_bounds__(256) void k_imp3(
    const float* __restrict__ XI, const double* __restrict__ S2,
    const float* __restrict__ W3, float* __restrict__ Z, double* __restrict__ S3,
    double invRows)
{
    __shared__ double red[4];
    int tid = threadIdx.x; int grp = tid>>6, ch = tid&63;
    int ent = blockIdx.x*4 + grp;
    float x0 = XI[(size_t)ent*128+ch], x1 = XI[(size_t)ent*128+64+ch];
    float s = qbn_s(S2, ch, invRows);
    float u0 = x0/s, u1 = x1/s;
    float mod = sqrtf(pair_m2(u0,u1));
    float cf = mod / fmaxf(1.f, mod);
    double w3 = (double)W3[ch];
    double v0 = (double)__fmul_rn(u0,cf) * w3;
    double v1 = (double)__fmul_rn(u1,cf) * w3;
#pragma unroll
    for (int m = 1; m < 64; m <<= 1) { v0 += __shfl_xor(v0,m,64); v1 += __shfl_xor(v1,m,64); }
    if (ch == 0) {
        float z0 = (float)v0, z1 = (float)v1;
        Z[(size_t)ent*2] = z0; Z[(size_t)ent*2+1] = z1;
        red[grp] = (double)z0*z0 + (double)z1*z1;
    }
    __syncthreads();
    if (tid == 0) atomicAdd(&S3[blockIdx.x & 15], red[0]+red[1]+red[2]+red[3]);
}

// ---- move_vec + oaq head + output cols 0..5. ----
__global__ __launch_bounds__(256) void k_final_small(
    const float* __restrict__ Zie, const float* __restrict__ Zia,
    const double* __restrict__ Sie3, const double* __restrict__ Sia3,
    const float* __restrict__ SFb,
    const float* __restrict__ Woa1, const float* __restrict__ boa1,
    const float* __restrict__ Woa2, const float* __restrict__ boa2,
    float* __restrict__ out, double invRows)
{
    __shared__ float sflds[4][64];
    int tid = threadIdx.x; int grp = tid>>6, ch = tid&63;
    int agent = blockIdx.x*4 + grp;
    float sie = sqrtf((float)(sum16sd(Sie3)*invRows) + EPSF);
    float sia = sqrtf((float)(sum16sd(Sia3)*invRows) + EPSF);
    double pv0 = 0.0, pv1 = 0.0;
    if (ch < NEN) {
        int ent = agent*NEN + ch;
        float z0 = Zie[(size_t)ent*2]/sie, z1 = Zie[(size_t)ent*2+1]/sie;
        float mod = sqrtf(pair_m2(z0,z1)); float cf = mod/fmaxf(1.f,mod);
        pv0 = (double)__fmul_rn(z0,cf); pv1 = (double)__fmul_rn(z1,cf);
        z0 = Zia[(size_t)ent*2]/sia; z1 = Zia[(size_t)ent*2+1]/sia;
        mod = sqrtf(pair_m2(z0,z1)); cf = mod/fmaxf(1.f,mod);
        pv0 += (double)__fmul_rn(z0,cf); pv1 += (double)__fmul_rn(z1,cf);
    }
#pragma unroll
    for (int m = 1; m < 64; m <<= 1) { pv0 += __shfl_xor(pv0,m,64); pv1 += __shfl_xor(pv1,m,64); }
    sflds[grp][ch] = SFb[(size_t)agent*64+ch];
    __syncthreads();
    double hd = (double)boa1[ch];
#pragma unroll
    for (int k = 0; k < 64; ++k) hd += (double)sflds[grp][k]*(double)Woa1[k*64+ch];
    float h = fmaxf((float)hd, 0.f);
    double q0 = (double)h*(double)Woa2[ch*3+0];
    double q1 = (double)h*(double)Woa2[ch*3+1];
    double q2 = (double)h*(double)Woa2[ch*3+2];
#pragma unroll
    for (int m = 1; m < 64; m <<= 1) { q0 += __shfl_xor(q0,m,64); q1 += __shfl_xor(q1,m,64); q2 += __shfl_xor(q2,m,64); }
    if (ch == 0) {
        float oaq0 = (float)(q0 + (double)boa2[0]);
        float oaq1 = (float)(q1 + (double)boa2[1]);
        float mmq  = (float)(q2 + (double)boa2[2]);
        float mv0 = (float)pv0, mv1 = (float)pv1;
        float* o = out + (size_t)agent*16;
        o[0] = oaq0; o[1] = oaq1;
        o[2] = mmq + mv1; o[3] = mmq - mv1;
        o[4] = mmq + mv0; o[5] = mmq - mv0;
    }
}

// ---- Attention MLP (128->128->64->1), 8 rows/block. ----
__global__ __launch_bounds__(256) void k_attn(
    const float* __restrict__ SFb, const float* __restrict__ XE,
    const float* __restrict__ W1, const float* __restrict__ b1,
    const float* __restrict__ W2, const float* __restrict__ b2,
    const float* __restrict__ W3, const float* __restrict__ b3,
    float* __restrict__ out)
{
    __shared__ float atf[8][128];
    __shared__ float h1[8][128];
    __shared__ float h2[8][64];
    int tid = threadIdx.x;
    int row0 = blockIdx.x*8;
#pragma unroll
    for (int i = 0; i < 4; ++i) {
        int idx = tid + i*256; int r = idx>>7; int j = idx&127;
        int ent = row0 + r; int agent = ent/NEN;
        float v;
        if (j < 64) v = SFb[(size_t)agent*64+j];
        else {
            float x0 = XE[(size_t)ent*128 + (j-64)];
            float x1 = XE[(size_t)ent*128 + 64 + (j-64)];
            v = pair_m2(x0,x1);
        }
        atf[r][j] = v;
    }
    __syncthreads();
    {
        int j = tid&127, rr = tid>>7;
        double bb = (double)b1[j];
        double a0=bb, a1=bb, a2=bb, a3=bb;
        for (int k = 0; k < 128; ++k) {
            double w = (double)W1[k*128+j];
            a0 += (double)atf[rr*4+0][k]*w;
            a1 += (double)atf[rr*4+1][k]*w;
            a2 += (double)atf[rr*4+2][k]*w;
            a3 += (double)atf[rr*4+3][k]*w;
        }
        h1[rr*4+0][j] = fmaxf((float)a0, 0.f);
        h1[rr*4+1][j] = fmaxf((float)a1, 0.f);
        h1[rr*4+2][j] = fmaxf((float)a2, 0.f);
        h1[rr*4+3][j] = fmaxf((float)a3, 0.f);
    }
    __syncthreads();
    {
        int j2 = tid&63, rr2 = tid>>6;
        double bb = (double)b2[j2];
        double a0=bb, a1=bb;
        for (int k = 0; k < 128; ++k) {
            double w = (double)W2[k*64+j2];
            a0 += (double)h1[rr2*2+0][k]*w;
            a1 += (double)h1[rr2*2+1][k]*w;
        }
        h2[rr2*2+0][j2] = fmaxf((float)a0, 0.f);
        h2[rr2*2+1][j2] = fmaxf((float)a1, 0.f);
    }
    __syncthreads();
    {
        int r3 = tid>>5, l3 = tid&31;
        double s = (double)h2[r3][l3]*(double)W3[l3] + (double)h2[r3][l3+32]*(double)W3[l3+32];
#pragma unroll
        for (int m = 1; m < 32; m <<= 1) s += __shfl_xor(s,m,64);
        if (l3 == 0) {
            int ent = row0 + r3; int agent = ent/NEN; int e = ent%NEN;
            out[(size_t)agent*16 + 6 + e] = (float)(s + (double)b3[0]);
        }
    }
}

extern "C" void kernel_launch(void* const* d_in, const int* in_sizes, int n_in,
                              void* d_out, int out_size, void* d_ws, size_t ws_size,
                              hipStream_t stream) {
    const float* own  = (const float*)d_in[0];
    const float* ef   = (const float*)d_in[1];
    const float* af   = (const float*)d_in[2];
    const float* W_e1 = (const float*)d_in[3];
    const float* W_e2 = (const float*)d_in[4];
    const float* W_a1 = (const float*)d_in[5];
    const float* W_a2 = (const float*)d_in[6];
    const float* W_f1 = (const float*)d_in[7];
    const float* W_f2 = (const float*)d_in[8];
    const float* W_ie1= (const float*)d_in[9];
    const float* W_ie2= (const float*)d_in[10];
    const float* W_ie3= (const float*)d_in[11];
    const float* W_ia1= (const float*)d_in[12];
    const float* W_ia2= (const float*)d_in[13];
    const float* W_ia3= (const float*)d_in[14];
    const float* W_oa1= (const float*)d_in[15];
    const float* b_oa1= (const float*)d_in[16];
    const float* W_oa2= (const float*)d_in[17];
    const float* b_oa2= (const float*)d_in[18];
    const float* W_at1= (const float*)d_in[19];
    const float* b_at1= (const float*)d_in[20];
    const float* W_at2= (const float*)d_in[21];
    const float* b_at2= (const float*)d_in[22];
    const float* W_at3= (const float*)d_in[23];
    const float* b_at3= (const float*)d_in[24];
    float* out = (float*)d_out;
    float* wsf = (float*)d_ws;
    double* Sd = (double*)d_ws;

    // f32-unit layout after the f64 S-region (~165 MB total)
    size_t o = (size_t)NDOUBLES*2;
    float*  X_E  = wsf + o; o += (size_t)NEE*128;        // per-pair e-chain
    float*  X_A  = wsf + o; o += (size_t)NAE*128;        // per-pair a-chain
    float*  F1   = wsf + o; o += (size_t)NAG*128;
    float*  SFb  = wsf + o; o += (size_t)NAG*64;
    float*  VT_IE = wsf + o; o += (size_t)NAG*128;
    float*  VT_IA = wsf + o; o += (size_t)NAG*128;
    float*  XI   = wsf + o; o += (size_t)NEE*128;        // shared e- then a-chain
    float*  Z_IE = wsf + o; o += (size_t)NEE*2;
    float*  Z_IA = wsf + o; o += (size_t)NEE*2;

    double* S_E1 = Sd + DOFF_SE1;  double* S_E2 = Sd + DOFF_SE2;
    double* S_A1 = Sd + DOFF_SA1;  double* S_A2 = Sd + DOFF_SA2;
    double* S_F1 = Sd + DOFF_SF1;  double* S_F2 = Sd + DOFF_SF2;
    double* S_IE1= Sd + DOFF_SIE1; double* S_IE2= Sd + DOFF_SIE2;
    double* S_IA1= Sd + DOFF_SIA1; double* S_IA2= Sd + DOFF_SIA2;
    double* S_IE3= Sd + DOFF_SIE3; double* S_IA3= Sd + DOFF_SIA3;

    const double invRe = 1.0/(double)(NEE*2);
    const double invRa = 1.0/(double)(NAE*2);
    const double invRf = 1.0/(double)(NAG*2);

    hipMemsetAsync(Sd, 0, (size_t)NDOUBLES*sizeof(double), stream);

    k_build_pair<<<NEE/2, 256, 0, stream>>>(ef, own, W_e1, X_E, S_E1, NEN);
    k_build_pair<<<NAE/2, 256, 0, stream>>>(af, own, W_a1, X_A, S_A1, NALY);
    k_pair_layer<<<NEE/4, 256, 0, stream>>>(X_E, S_E1, S_E2, W_e2, invRe);
    k_pair_layer<<<NAE/4, 256, 0, stream>>>(X_A, S_A1, S_A2, W_a2, invRa);
    k_finalize_pair<<<NEE*128/256, 256, 0, stream>>>(X_E, S_E2, invRe);
    k_finalize_pair<<<NAE*128/256, 256, 0, stream>>>(X_A, S_A2, invRa);
    k_pool_f1<<<NAG/4, 256, 0, stream>>>(X_E, X_A, W_f1, F1, S_F1);
    k_pair_layer<<<NAG/4, 256, 0, stream>>>(F1, S_F1, S_F2, W_f2, invRf);
    k_vf_vtop<<<NAG/4, 256, 0, stream>>>(F1, S_F2, SFb, W_ie1, W_ia1, VT_IE, VT_IA, invRf);
    // e-importance chain
    k_imp1<<<NEE/2, 256, 0, stream>>>(X_E, VT_IE, W_ie1, XI, S_IE1);
    k_pair_layer<<<NEE/4, 256, 0, stream>>>(XI, S_IE1, S_IE2, W_ie2, invRe);
    k_imp3<<<NEE/4, 256, 0, stream>>>(XI, S_IE2, W_ie3, Z_IE, S_IE3, invRe);
    // a-importance chain (same cat input; XI reused)
    k_imp1<<<NEE/2, 256, 0, stream>>>(X_E, VT_IA, W_ia1, XI, S_IA1);
    k_pair_layer<<<NEE/4, 256, 0, stream>>>(XI, S_IA1, S_IA2, W_ia2, invRe);
    k_imp3<<<NEE/4, 256, 0, stream>>>(XI, S_IA2, W_ia3, Z_IA, S_IA3, invRe);

    k_final_small<<<NAG/4, 256, 0, stream>>>(Z_IE, Z_IA, S_IE3, S_IA3, SFb,
                                             W_oa1, b_oa1, W_oa2, b_oa2, out, invRe);
    k_attn<<<NEE/8, 256, 0, stream>>>(SFb, X_E, W_at1, b_at1, W_at2, b_at2,
                                      W_at3, b_at3, out);
}

// Round 11
// 1528.268 us; speedup vs baseline: 1.0629x; 1.0629x over previous
//
#include <hip/hip_runtime.h>
#include <math.h>

// Problem constants
#define BATCH 1024
#define NA 10
#define NEN 10
#define NALY 9
#define NAG (BATCH*NA)          // 10240
#define NEE (NAG*NEN)           // 102400
#define NAE (NAG*NALY)          // 92160
#define EPSF 1e-5f

// f64 replicated qbn-sum buffers (16 replicas), at start of ws (double units)
#define DOFF_SE1 0
#define DOFF_SE2 1024
#define DOFF_SA1 2048
#define DOFF_SA2 3072
#define DOFF_SF1 4096
#define DOFF_SF2 5120
#define DOFF_SIE1 6144
#define DOFF_SIE2 7168
#define DOFF_SIA1 8192
#define DOFF_SIA2 9216
#define DOFF_SIE3 10240
#define DOFF_SIA3 10256
#define NDOUBLES 16384

__device__ __forceinline__ double sum16vd(const double* __restrict__ S, int ch) {
    double s = 0.0;
#pragma unroll
    for (int r = 0; r < 16; ++r) s += S[r*64 + ch];
    return s;
}
__device__ __forceinline__ double sum16sd(const double* __restrict__ S) {
    double s = 0.0;
#pragma unroll
    for (int r = 0; r < 16; ++r) s += S[r];
    return s;
}
// qbn scale: s = fl32(sqrt(fl32(exact_mean) + eps))
__device__ __forceinline__ float qbn_s(const double* __restrict__ S, int ch, double invRows) {
    float m = (float)(sum16vd(S, ch)*invRows);
    return sqrtf(m + EPSF);
}
__device__ __forceinline__ void red_to_S(const double* red, double* S, int bid, int tid) {
    if (tid < 64) {
        double v = red[tid] + red[tid+64] + red[tid+128] + red[tid+192];
        atomicAdd(&S[(bid & 15)*64 + tid], v);
    }
}
// np-lattice pair mod^2: fl(fl(x0^2)+fl(x1^2)) (no FMA contraction)
__device__ __forceinline__ float pair_m2(float x0, float x1) {
    return __fadd_rn(__fmul_rn(x0,x0), __fmul_rn(x1,x1));
}

// ---- build_vec + layer1 GEMM, per pair element; f32 FMA dot, REVERSED k
//      (the passing R10 configuration — FROZEN, feeds pool argmax). ----
__global__ __launch_bounds__(256) void k_build_pair(
    const float* __restrict__ feats, const float* __restrict__ own,
    const float* __restrict__ W1, float* __restrict__ X,
    double* __restrict__ S1, int nEntPerAgent)
{
    __shared__ float wlds[19*64];
    __shared__ float g[2][19];
    __shared__ float pxy[2][2];
    __shared__ double red[256];
    int tid = threadIdx.x;
    for (int i = tid; i < 19*64; i += 256) wlds[i] = W1[i];
    int l = tid >> 7, c = (tid >> 6) & 1, ch = tid & 63;
    int ent = blockIdx.x*2 + l;
    if (c == 0 && ch < 19) {
        const float* f = feats + (size_t)ent*9;
        int agent = ent / nEntPerAgent;
        float px = f[2], py = f[3];
        float pm = sqrtf(__fadd_rn(__fmul_rn(px,px), __fmul_rn(py,py)));
        float val;
        if (ch == 0) val = 1.f;
        else if (ch < 8) {
            int j = ch - 1;
            int fi = (j < 2) ? j : (j + 2);
            float o = f[fi];
            float om = sqrtf(__fmul_rn(__fmul_rn(2.0f,o),o));
            val = (pm == 0.f) ? 0.f : __fdiv_rn(om, pm);
        } else {
            float o = own[(size_t)agent*11 + (ch-8)];
            float t = __fmul_rn(o,o);
            float om = sqrtf(__fadd_rn(t,t));
            val = (pm == 0.f) ? 0.f : __fdiv_rn(om, pm);
        }
        g[l][ch] = val;
        if (ch == 0) { pxy[l][0] = px; pxy[l][1] = py; }
    }
    __syncthreads();
    float pc = pxy[l][c];
    float acc = 0.f;
#pragma unroll
    for (int k = 18; k >= 0; --k) {            // REVERSED k order (frozen)
        float ev = __fmul_rn(pc, g[l][k]);
        acc = fmaf(ev, wlds[k*64+ch], acc);
    }
    X[(size_t)ent*128 + c*64 + ch] = acc;
    red[tid] = (double)acc * (double)acc;
    __syncthreads();
    red_to_S(red, S1, blockIdx.x, tid);
}

// ---- pair layer: qbn + qrelu + 64x64 GEMM (f32 FMA, REVERSED k). FROZEN. --
__global__ __launch_bounds__(256) void k_pair_layer(
    float* __restrict__ X, const double* __restrict__ Sin, double* __restrict__ Sout,
    const float* __restrict__ W, double invRows)
{
    __shared__ float wlds[4096];
    __shared__ float ybuf[4][2][64];
    __shared__ double red[256];
    int tid = threadIdx.x;
    for (int i = tid; i < 4096; i += 256) wlds[i] = W[i];
    int grp = tid>>6, ch = tid&63;
    int row = blockIdx.x*4 + grp;
    float x0 = X[(size_t)row*128+ch], x1 = X[(size_t)row*128+64+ch];
    float s = qbn_s(Sin, ch, invRows);
    float u0 = x0/s, u1 = x1/s;
    float mod = sqrtf(pair_m2(u0,u1));
    float cf = mod / fmaxf(1.f, mod);
    ybuf[grp][0][ch] = __fmul_rn(u0,cf);
    ybuf[grp][1][ch] = __fmul_rn(u1,cf);
    __syncthreads();
    float a0 = 0.f, a1 = 0.f;
#pragma unroll
    for (int k = 63; k >= 0; --k) {            // REVERSED k order (frozen)
        float w = wlds[k*64+ch];
        a0 = fmaf(ybuf[grp][0][k], w, a0);
        a1 = fmaf(ybuf[grp][1][k], w, a1);
    }
    X[(size_t)row*128+ch] = a0; X[(size_t)row*128+64+ch] = a1;
    red[tid] = (double)a0*a0 + (double)a1*a1;
    __syncthreads();
    red_to_S(red, Sout, blockIdx.x, tid);
}

// ---- Finalize: y = qrelu(qbn(x)) per pair element, in place. FROZEN. ----
__global__ __launch_bounds__(256) void k_finalize_pair(
    float* __restrict__ X, const double* __restrict__ S2, double invRows)
{
    int idx = blockIdx.x*256 + threadIdx.x;
    int ch = idx & 63, c = (idx>>6) & 1;
    float x  = X[idx];
    float xo = X[idx^64];
    __syncthreads();
    float s = qbn_s(S2, ch, invRows);
    float u  = x/s;
    float uo = xo/s;
    float u0 = (c==0) ? u : uo, u1 = (c==0) ? uo : u;
    float mod = sqrtf(pair_m2(u0,u1));
    float cf = mod / fmaxf(1.f, mod);
    X[idx] = __fmul_rn(u, cf);
}

// ---- Pool (argmax over 19, enemies first, strict first-max) + f1. FROZEN. --
__global__ __launch_bounds__(256) void k_pool_f1(
    const float* __restrict__ XE, const float* __restrict__ XA,
    const float* __restrict__ Wf1, float* __restrict__ F1, double* __restrict__ Sf1)
{
    __shared__ float wlds[4096];
    __shared__ float v[4][2][64];
    __shared__ double red[256];
    int tid = threadIdx.x;
    for (int i = tid; i < 4096; i += 256) wlds[i] = Wf1[i];
    int grp = tid>>6, ch = tid&63;
    int agent = blockIdx.x*4 + grp;
    float best = -1.f, v0 = 0.f, v1 = 0.f;
    for (int e = 0; e < NEN; ++e) {
        size_t b = (size_t)(agent*NEN+e)*128;
        float x0 = XE[b+ch], x1 = XE[b+64+ch];
        float m2 = pair_m2(x0,x1);
        if (m2 > best) { best = m2; v0 = x0; v1 = x1; }
    }
    for (int l = 0; l < NALY; ++l) {
        size_t b = (size_t)(agent*NALY+l)*128;
        float x0 = XA[b+ch], x1 = XA[b+64+ch];
        float m2 = pair_m2(x0,x1);
        if (m2 > best) { best = m2; v0 = x0; v1 = x1; }
    }
    v[grp][0][ch] = v0; v[grp][1][ch] = v1;
    __syncthreads();
    float a0 = 0.f, a1 = 0.f;
#pragma unroll
    for (int k = 0; k < 64; ++k) {
        float w = wlds[k*64+ch];
        a0 = fmaf(v[grp][0][k], w, a0);
        a1 = fmaf(v[grp][1][k], w, a1);
    }
    F1[(size_t)agent*128+ch] = a0; F1[(size_t)agent*128+64+ch] = a1;
    red[tid] = (double)a0*a0 + (double)a1*a1;
    __syncthreads();
    red_to_S(red, Sf1, blockIdx.x, tid);
}

// ---- vf finalize + SFb + VT = vf @ W1top for both imp chains. ----
__global__ __launch_bounds__(256) void k_vf_vtop(
    const float* __restrict__ F1, const double* __restrict__ Sf2,
    float* __restrict__ SFb,
    const float* __restrict__ Wie1, const float* __restrict__ Wia1,
    float* __restrict__ VTie, float* __restrict__ VTia, double invRows)
{
    __shared__ float wie[4096];
    __shared__ float wia[4096];
    __shared__ float vf[4][2][64];
    int tid = threadIdx.x;
    for (int i = tid; i < 4096; i += 256) { wie[i] = Wie1[i]; wia[i] = Wia1[i]; }
    int grp = tid>>6, ch = tid&63;
    int agent = blockIdx.x*4 + grp;
    float x0 = F1[(size_t)agent*128+ch], x1 = F1[(size_t)agent*128+64+ch];
    float s = qbn_s(Sf2, ch, invRows);
    float u0 = x0/s, u1 = x1/s;
    float mod = sqrtf(pair_m2(u0,u1));
    float cf = mod / fmaxf(1.f, mod);
    float y0 = __fmul_rn(u0,cf), y1 = __fmul_rn(u1,cf);
    vf[grp][0][ch] = y0; vf[grp][1][ch] = y1;
    SFb[(size_t)agent*64+ch] = pair_m2(y0,y1);
    __syncthreads();
    float a0=0.f,a1=0.f,b0=0.f,b1=0.f;
#pragma unroll
    for (int k = 0; k < 64; ++k) {
        float f0 = vf[grp][0][k], f1 = vf[grp][1][k];
        a0 = fmaf(f0, wie[k*64+ch], a0); a1 = fmaf(f1, wie[k*64+ch], a1);
        b0 = fmaf(f0, wia[k*64+ch], b0); b1 = fmaf(f1, wia[k*64+ch], b1);
    }
    VTie[(size_t)agent*128+ch] = a0; VTie[(size_t)agent*128+64+ch] = a1;
    VTia[(size_t)agent*128+ch] = b0; VTia[(size_t)agent*128+64+ch] = b1;
}

// ---- imp layer1: XI = VT + XE @ W1bot (f32 FMA), f64 stats S1. ----
__global__ __launch_bounds__(256) void k_imp1(
    const float* __restrict__ XE, const float* __restrict__ VT,
    const float* __restrict__ W1, float* __restrict__ XI, double* __restrict__ S1)
{
    __shared__ float wlds[4096];
    __shared__ float xt[256];
    __shared__ double red[256];
    int tid = threadIdx.x;
    for (int i = tid; i < 4096; i += 256) wlds[i] = W1[4096 + i];
    int l = tid>>7, c = (tid>>6)&1, ch = tid&63;
    int ent = blockIdx.x*2 + l;
    int agent = ent / NEN;
    xt[tid] = XE[(size_t)blockIdx.x*256 + tid];
    __syncthreads();
    const float* xr = &xt[l*128 + c*64];
    float acc = VT[(size_t)agent*128 + c*64 + ch];
#pragma unroll
    for (int k = 0; k < 64; ++k) acc = fmaf(xr[k], wlds[k*64+ch], acc);
    XI[(size_t)ent*128 + c*64 + ch] = acc;
    red[tid] = (double)acc*(double)acc;
    __syncthreads();
    red_to_S(red, S1, blockIdx.x, tid);
}

// ---- imp layer3: qbn(S2)+qrelu then dot W3 -> Z, stats S3. ----
__global__ __launch_bounds__(256) void k_imp3(
    const float* __restrict__ XI, const double* __restrict__ S2,
    const float* __restrict__ W3, float* __restrict__ Z, double* __restrict__ S3,
    double invRows)
{
    __shared__ double red[4];
    int tid = threadIdx.x; int grp = tid>>6, ch = tid&63;
    int ent = blockIdx.x*4 + grp;
    float x0 = XI[(size_t)ent*128+ch], x1 = XI[(size_t)ent*128+64+ch];
    float s = qbn_s(S2, ch, invRows);
    float u0 = x0/s, u1 = x1/s;
    float mod = sqrtf(pair_m2(u0,u1));
    float cf = mod / fmaxf(1.f, mod);
    double w3 = (double)W3[ch];
    double v0 = (double)__fmul_rn(u0,cf) * w3;
    double v1 = (double)__fmul_rn(u1,cf) * w3;
#pragma unroll
    for (int m = 1; m < 64; m <<= 1) { v0 += __shfl_xor(v0,m,64); v1 += __shfl_xor(v1,m,64); }
    if (ch == 0) {
        float z0 = (float)v0, z1 = (float)v1;
        Z[(size_t)ent*2] = z0; Z[(size_t)ent*2+1] = z1;
        red[grp] = (double)z0*z0 + (double)z1*z1;
    }
    __syncthreads();
    if (tid == 0) atomicAdd(&S3[blockIdx.x & 15], red[0]+red[1]+red[2]+red[3]);
}

// ---- move_vec + oaq head + output cols 0..5. (unchanged) ----
__global__ __launch_bounds__(256) void k_final_small(
    const float* __restrict__ Zie, const float* __restrict__ Zia,
    const double* __restrict__ Sie3, const double* __restrict__ Sia3,
    const float* __restrict__ SFb,
    const float* __restrict__ Woa1, const float* __restrict__ boa1,
    const float* __restrict__ Woa2, const float* __restrict__ boa2,
    float* __restrict__ out, double invRows)
{
    __shared__ float sflds[4][64];
    int tid = threadIdx.x; int grp = tid>>6, ch = tid&63;
    int agent = blockIdx.x*4 + grp;
    float sie = sqrtf((float)(sum16sd(Sie3)*invRows) + EPSF);
    float sia = sqrtf((float)(sum16sd(Sia3)*invRows) + EPSF);
    double pv0 = 0.0, pv1 = 0.0;
    if (ch < NEN) {
        int ent = agent*NEN + ch;
        float z0 = Zie[(size_t)ent*2]/sie, z1 = Zie[(size_t)ent*2+1]/sie;
        float mod = sqrtf(pair_m2(z0,z1)); float cf = mod/fmaxf(1.f,mod);
        pv0 = (double)__fmul_rn(z0,cf); pv1 = (double)__fmul_rn(z1,cf);
        z0 = Zia[(size_t)ent*2]/sia; z1 = Zia[(size_t)ent*2+1]/sia;
        mod = sqrtf(pair_m2(z0,z1)); cf = mod/fmaxf(1.f,mod);
        pv0 += (double)__fmul_rn(z0,cf); pv1 += (double)__fmul_rn(z1,cf);
    }
#pragma unroll
    for (int m = 1; m < 64; m <<= 1) { pv0 += __shfl_xor(pv0,m,64); pv1 += __shfl_xor(pv1,m,64); }
    sflds[grp][ch] = SFb[(size_t)agent*64+ch];
    __syncthreads();
    double hd = (double)boa1[ch];
#pragma unroll
    for (int k = 0; k < 64; ++k) hd += (double)sflds[grp][k]*(double)Woa1[k*64+ch];
    float h = fmaxf((float)hd, 0.f);
    double q0 = (double)h*(double)Woa2[ch*3+0];
    double q1 = (double)h*(double)Woa2[ch*3+1];
    double q2 = (double)h*(double)Woa2[ch*3+2];
#pragma unroll
    for (int m = 1; m < 64; m <<= 1) { q0 += __shfl_xor(q0,m,64); q1 += __shfl_xor(q1,m,64); q2 += __shfl_xor(q2,m,64); }
    if (ch == 0) {
        float oaq0 = (float)(q0 + (double)boa2[0]);
        float oaq1 = (float)(q1 + (double)boa2[1]);
        float mmq  = (float)(q2 + (double)boa2[2]);
        float mv0 = (float)pv0, mv1 = (float)pv1;
        float* o = out + (size_t)agent*16;
        o[0] = oaq0; o[1] = oaq1;
        o[2] = mmq + mv1; o[3] = mmq - mv1;
        o[4] = mmq + mv0; o[5] = mmq - mv0;
    }
}

// ---- Attention MLP (128->128->64->1), f32 FMA, 16 rows/block. ----
// Smooth path only (cols 6..15), ~1e-6 shift vs f64; 10x threshold margin.
__global__ __launch_bounds__(256) void k_attn(
    const float* __restrict__ SFb, const float* __restrict__ XE,
    const float* __restrict__ W1, const float* __restrict__ b1,
    const float* __restrict__ W2, const float* __restrict__ b2,
    const float* __restrict__ W3, const float* __restrict__ b3,
    float* __restrict__ out)
{
    __shared__ float atf[16][128];
    __shared__ float h1[16][128];
    __shared__ float h2[16][64];
    int tid = threadIdx.x;
    int row0 = blockIdx.x*16;
#pragma unroll
    for (int i = 0; i < 8; ++i) {
        int idx = tid + i*256; int r = idx>>7; int j = idx&127;
        int ent = row0 + r; int agent = ent/NEN;
        float v;
        if (j < 64) v = SFb[(size_t)agent*64+j];
        else {
            float x0 = XE[(size_t)ent*128 + (j-64)];
            float x1 = XE[(size_t)ent*128 + 64 + (j-64)];
            v = pair_m2(x0,x1);
        }
        atf[r][j] = v;
    }
    __syncthreads();
    {   // layer1: j = tid&127, rows (tid>>7)*8 .. +7
        int j = tid & 127, rr = tid >> 7;
        float acc[8];
        float bb = b1[j];
#pragma unroll
        for (int r = 0; r < 8; ++r) acc[r] = bb;
        for (int k = 0; k < 128; ++k) {
            float w = W1[k*128+j];
#pragma unroll
            for (int r = 0; r < 8; ++r)
                acc[r] = fmaf(atf[rr*8+r][k], w, acc[r]);
        }
#pragma unroll
        for (int r = 0; r < 8; ++r) h1[rr*8+r][j] = fmaxf(acc[r], 0.f);
    }
    __syncthreads();
    {   // layer2: j2 = tid&63, rows (tid>>6)*4 .. +3
        int j2 = tid & 63, rr2 = tid >> 6;
        float a[4];
        float bb = b2[j2];
#pragma unroll
        for (int r = 0; r < 4; ++r) a[r] = bb;
        for (int k = 0; k < 128; ++k) {
            float w = W2[k*64+j2];
#pragma unroll
            for (int r = 0; r < 4; ++r) a[r] = fmaf(h1[rr2*4+r][k], w, a[r]);
        }
#pragma unroll
        for (int r = 0; r < 4; ++r) h2[rr2*4+r][j2] = fmaxf(a[r], 0.f);
    }
    __syncthreads();
    {   // layer3: 16 rows, 16 lanes each (within-wave groups)
        int r3 = tid >> 4, l3 = tid & 15;
        float s = h2[r3][l3]*W3[l3] + h2[r3][l3+16]*W3[l3+16]
                + h2[r3][l3+32]*W3[l3+32] + h2[r3][l3+48]*W3[l3+48];
#pragma unroll
        for (int m = 1; m < 16; m <<= 1) s += __shfl_xor(s, m, 64);
        if (l3 == 0) {
            int ent = row0 + r3; int agent = ent/NEN; int e = ent%NEN;
            out[(size_t)agent*16 + 6 + e] = s + b3[0];
        }
    }
}

extern "C" void kernel_launch(void* const* d_in, const int* in_sizes, int n_in,
                              void* d_out, int out_size, void* d_ws, size_t ws_size,
                              hipStream_t stream) {
    const float* own  = (const float*)d_in[0];
    const float* ef   = (const float*)d_in[1];
    const float* af   = (const float*)d_in[2];
    const float* W_e1 = (const float*)d_in[3];
    const float* W_e2 = (const float*)d_in[4];
    const float* W_a1 = (const float*)d_in[5];
    const float* W_a2 = (const float*)d_in[6];
    const float* W_f1 = (const float*)d_in[7];
    const float* W_f2 = (const float*)d_in[8];
    const float* W_ie1= (const float*)d_in[9];
    const float* W_ie2= (const float*)d_in[10];
    const float* W_ie3= (const float*)d_in[11];
    const float* W_ia1= (const float*)d_in[12];
    const float* W_ia2= (const float*)d_in[13];
    const float* W_ia3= (const float*)d_in[14];
    const float* W_oa1= (const float*)d_in[15];
    const float* b_oa1= (const float*)d_in[16];
    const float* W_oa2= (const float*)d_in[17];
    const float* b_oa2= (const float*)d_in[18];
    const float* W_at1= (const float*)d_in[19];
    const float* b_at1= (const float*)d_in[20];
    const float* W_at2= (const float*)d_in[21];
    const float* b_at2= (const float*)d_in[22];
    const float* W_at3= (const float*)d_in[23];
    const float* b_at3= (const float*)d_in[24];
    float* out = (float*)d_out;
    float* wsf = (float*)d_ws;
    double* Sd = (double*)d_ws;

    // f32-unit layout after the f64 S-region (~165 MB total)
    size_t o = (size_t)NDOUBLES*2;
    float*  X_E  = wsf + o; o += (size_t)NEE*128;        // per-pair e-chain
    float*  X_A  = wsf + o; o += (size_t)NAE*128;        // per-pair a-chain
    float*  F1   = wsf + o; o += (size_t)NAG*128;
    float*  SFb  = wsf + o; o += (size_t)NAG*64;
    float*  VT_IE = wsf + o; o += (size_t)NAG*128;
    float*  VT_IA = wsf + o; o += (size_t)NAG*128;
    float*  XI   = wsf + o; o += (size_t)NEE*128;        // shared e- then a-chain
    float*  Z_IE = wsf + o; o += (size_t)NEE*2;
    float*  Z_IA = wsf + o; o += (size_t)NEE*2;

    double* S_E1 = Sd + DOFF_SE1;  double* S_E2 = Sd + DOFF_SE2;
    double* S_A1 = Sd + DOFF_SA1;  double* S_A2 = Sd + DOFF_SA2;
    double* S_F1 = Sd + DOFF_SF1;  double* S_F2 = Sd + DOFF_SF2;
    double* S_IE1= Sd + DOFF_SIE1; double* S_IE2= Sd + DOFF_SIE2;
    double* S_IA1= Sd + DOFF_SIA1; double* S_IA2= Sd + DOFF_SIA2;
    double* S_IE3= Sd + DOFF_SIE3; double* S_IA3= Sd + DOFF_SIA3;

    const double invRe = 1.0/(double)(NEE*2);
    const double invRa = 1.0/(double)(NAE*2);
    const double invRf = 1.0/(double)(NAG*2);

    hipMemsetAsync(Sd, 0, (size_t)NDOUBLES*sizeof(double), stream);

    k_build_pair<<<NEE/2, 256, 0, stream>>>(ef, own, W_e1, X_E, S_E1, NEN);
    k_build_pair<<<NAE/2, 256, 0, stream>>>(af, own, W_a1, X_A, S_A1, NALY);
    k_pair_layer<<<NEE/4, 256, 0, stream>>>(X_E, S_E1, S_E2, W_e2, invRe);
    k_pair_layer<<<NAE/4, 256, 0, stream>>>(X_A, S_A1, S_A2, W_a2, invRa);
    k_finalize_pair<<<NEE*128/256, 256, 0, stream>>>(X_E, S_E2, invRe);
    k_finalize_pair<<<NAE*128/256, 256, 0, stream>>>(X_A, S_A2, invRa);
    k_pool_f1<<<NAG/4, 256, 0, stream>>>(X_E, X_A, W_f1, F1, S_F1);
    k_pair_layer<<<NAG/4, 256, 0, stream>>>(F1, S_F1, S_F2, W_f2, invRf);
    k_vf_vtop<<<NAG/4, 256, 0, stream>>>(F1, S_F2, SFb, W_ie1, W_ia1, VT_IE, VT_IA, invRf);
    // e-importance chain
    k_imp1<<<NEE/2, 256, 0, stream>>>(X_E, VT_IE, W_ie1, XI, S_IE1);
    k_pair_layer<<<NEE/4, 256, 0, stream>>>(XI, S_IE1, S_IE2, W_ie2, invRe);
    k_imp3<<<NEE/4, 256, 0, stream>>>(XI, S_IE2, W_ie3, Z_IE, S_IE3, invRe);
    // a-importance chain (same cat input; XI reused)
    k_imp1<<<NEE/2, 256, 0, stream>>>(X_E, VT_IA, W_ia1, XI, S_IA1);
    k_pair_layer<<<NEE/4, 256, 0, stream>>>(XI, S_IA1, S_IA2, W_ia2, invRe);
    k_imp3<<<NEE/4, 256, 0, stream>>>(XI, S_IA2, W_ia3, Z_IA, S_IA3, invRe);

    k_final_small<<<NAG/4, 256, 0, stream>>>(Z_IE, Z_IA, S_IE3, S_IA3, SFb,
                                             W_oa1, b_oa1, W_oa2, b_oa2, out, invRe);
    k_attn<<<NEE/16, 256, 0, stream>>>(SFb, X_E, W_at1, b_at1, W_at2, b_at2,
                                       W_at3, b_at3, out);
}

// Round 12
// 801.065 us; speedup vs baseline: 2.0278x; 1.9078x over previous
//
#include <hip/hip_runtime.h>
#include <math.h>

// Problem constants
#define BATCH 1024
#define NA 10
#define NEN 10
#define NALY 9
#define NAG (BATCH*NA)          // 10240
#define NEE (NAG*NEN)           // 102400
#define NAE (NAG*NALY)          // 92160
#define EPSF 1e-5f

// f64 replicated qbn-sum buffers (16 replicas), at start of ws (double units)
#define DOFF_SE1 0
#define DOFF_SE2 1024
#define DOFF_SA1 2048
#define DOFF_SA2 3072
#define DOFF_SF1 4096
#define DOFF_SF2 5120
#define DOFF_SIE1 6144
#define DOFF_SIE2 7168
#define DOFF_SIA1 8192
#define DOFF_SIA2 9216
#define DOFF_SIE3 10240   // 16 replicas x stride 8 (one cache line each)
#define DOFF_SIA3 10368   // 16 replicas x stride 8
#define NDOUBLES 16384

__device__ __forceinline__ double sum16vd(const double* __restrict__ S, int ch) {
    double s = 0.0;
#pragma unroll
    for (int r = 0; r < 16; ++r) s += S[r*64 + ch];
    return s;
}
__device__ __forceinline__ double sum16sd8(const double* __restrict__ S) {
    double s = 0.0;
#pragma unroll
    for (int r = 0; r < 16; ++r) s += S[r*8];
    return s;
}
// qbn scale: s = fl32(sqrt(fl32(exact_mean) + eps))
__device__ __forceinline__ float qbn_s(const double* __restrict__ S, int ch, double invRows) {
    float m = (float)(sum16vd(S, ch)*invRows);
    return sqrtf(m + EPSF);
}
__device__ __forceinline__ void red_to_S(const double* red, double* S, int bid, int tid) {
    if (tid < 64) {
        double v = red[tid] + red[tid+64] + red[tid+128] + red[tid+192];
        atomicAdd(&S[(bid & 15)*64 + tid], v);
    }
}
// np-lattice pair mod^2: fl(fl(x0^2)+fl(x1^2)) (no FMA contraction)
__device__ __forceinline__ float pair_m2(float x0, float x1) {
    return __fadd_rn(__fmul_rn(x0,x0), __fmul_rn(x1,x1));
}

// ---- build_vec + layer1 GEMM; 8 ents/block, 4 ents/thread. Per-output
//      FP sequence identical to R10 (REVERSED k, FROZEN — feeds pool). ----
__global__ __launch_bounds__(256) void k_build_pair(
    const float* __restrict__ feats, const float* __restrict__ own,
    const float* __restrict__ W1, float* __restrict__ X,
    double* __restrict__ S1, int nEntPerAgent)
{
    __shared__ float wlds[19*64];
    __shared__ float g[8][19];
    __shared__ float pxy[8][2];
    __shared__ double red[256];
    int tid = threadIdx.x;
    for (int i = tid; i < 19*64; i += 256) wlds[i] = W1[i];
    if (tid < 152) {
        int el = tid / 19, chg = tid % 19;
        int ent = blockIdx.x*8 + el;
        const float* f = feats + (size_t)ent*9;
        int agent = ent / nEntPerAgent;
        float px = f[2], py = f[3];
        float pm = sqrtf(__fadd_rn(__fmul_rn(px,px), __fmul_rn(py,py)));
        float val;
        if (chg == 0) val = 1.f;
        else if (chg < 8) {
            int j = chg - 1;
            int fi = (j < 2) ? j : (j + 2);
            float o = f[fi];
            float om = sqrtf(__fmul_rn(__fmul_rn(2.0f,o),o));
            val = (pm == 0.f) ? 0.f : __fdiv_rn(om, pm);
        } else {
            float o = own[(size_t)agent*11 + (chg-8)];
            float t = __fmul_rn(o,o);
            float om = sqrtf(__fadd_rn(t,t));
            val = (pm == 0.f) ? 0.f : __fdiv_rn(om, pm);
        }
        g[el][chg] = val;
        if (chg == 0) { pxy[el][0] = px; pxy[el][1] = py; }
    }
    __syncthreads();
    int l = tid >> 7, c = (tid >> 6) & 1, ch = tid & 63;
    double lr = 0.0;
#pragma unroll
    for (int i = 0; i < 4; ++i) {
        int el = l + 2*i;
        int ent = blockIdx.x*8 + el;
        float pc = pxy[el][c];
        float acc = 0.f;
#pragma unroll
        for (int k = 18; k >= 0; --k) {            // REVERSED k (frozen)
            float ev = __fmul_rn(pc, g[el][k]);
            acc = fmaf(ev, wlds[k*64+ch], acc);
        }
        X[(size_t)ent*128 + c*64 + ch] = acc;
        lr += (double)acc * (double)acc;
    }
    red[tid] = lr;
    __syncthreads();
    red_to_S(red, S1, blockIdx.x, tid);
}

// ---- pair layer: qbn + qrelu + 64x64 GEMM; 16 rows/block, 4 rows/thread.
//      Per-output FP sequence identical to R10 (REVERSED k, FROZEN). ----
__global__ __launch_bounds__(256) void k_pair_layer(
    float* __restrict__ X, const double* __restrict__ Sin, double* __restrict__ Sout,
    const float* __restrict__ W, double invRows)
{
    __shared__ float wlds[4096];
    __shared__ float ybuf[16][64][2];
    __shared__ float ss[64];
    __shared__ double red[256];
    int tid = threadIdx.x;
    for (int i = tid; i < 4096; i += 256) wlds[i] = W[i];
    if (tid < 64) ss[tid] = qbn_s(Sin, tid, invRows);
    __syncthreads();
    int rgrp = tid>>6, ch = tid&63;
#pragma unroll
    for (int i = 0; i < 4; ++i) {
        int rl = rgrp + 4*i;
        size_t row = (size_t)blockIdx.x*16 + rl;
        float x0 = X[row*128+ch], x1 = X[row*128+64+ch];
        float s = ss[ch];
        float u0 = x0/s, u1 = x1/s;
        float mod = sqrtf(pair_m2(u0,u1));
        float cf = mod / fmaxf(1.f, mod);
        ybuf[rl][ch][0] = __fmul_rn(u0,cf);
        ybuf[rl][ch][1] = __fmul_rn(u1,cf);
    }
    __syncthreads();
    float a0[4] = {0.f,0.f,0.f,0.f};
    float a1[4] = {0.f,0.f,0.f,0.f};
#pragma unroll
    for (int k = 63; k >= 0; --k) {            // REVERSED k (frozen)
        float w = wlds[k*64+ch];
#pragma unroll
        for (int r = 0; r < 4; ++r) {
            float y0 = ybuf[rgrp + 4*r][k][0];   // broadcast within wave
            float y1 = ybuf[rgrp + 4*r][k][1];
            a0[r] = fmaf(y0, w, a0[r]);
            a1[r] = fmaf(y1, w, a1[r]);
        }
    }
    double lr = 0.0;
#pragma unroll
    for (int r = 0; r < 4; ++r) {
        size_t row = (size_t)blockIdx.x*16 + rgrp + 4*r;
        X[row*128+ch] = a0[r]; X[row*128+64+ch] = a1[r];
        lr += (double)a0[r]*a0[r] + (double)a1[r]*a1[r];
    }
    red[tid] = lr;
    __syncthreads();
    red_to_S(red, Sout, blockIdx.x, tid);
}

// ---- Finalize (E only): y = qrelu(qbn(x)), in place. Bit-identical ops. ----
__global__ __launch_bounds__(256) void k_finalize_pair(
    float* __restrict__ X, const double* __restrict__ S2, double invRows)
{
    __shared__ float ss[64];
    if (threadIdx.x < 64) ss[threadIdx.x] = qbn_s(S2, threadIdx.x, invRows);
    int idx = blockIdx.x*256 + threadIdx.x;
    int ch = idx & 63, c = (idx>>6) & 1;
    float x  = X[idx];
    float xo = X[idx^64];
    __syncthreads();
    float s = ss[ch];
    float u  = x/s;
    float uo = xo/s;
    float u0 = (c==0) ? u : uo, u1 = (c==0) ? uo : u;
    float mod = sqrtf(pair_m2(u0,u1));
    float cf = mod / fmaxf(1.f, mod);
    X[idx] = __fmul_rn(u, cf);
}

// ---- Pool + f1 GEMM, with ALLY finalize fused inline (same op sequence
//      as k_finalize_pair, so candidate bits are identical). ----
__global__ __launch_bounds__(256) void k_pool_f1(
    const float* __restrict__ XE, const float* __restrict__ XAraw,
    const double* __restrict__ SA2, double invRa,
    const float* __restrict__ Wf1, float* __restrict__ F1, double* __restrict__ Sf1)
{
    __shared__ float wlds[4096];
    __shared__ float v[4][2][64];
    __shared__ float ssa[64];
    __shared__ double red[256];
    int tid = threadIdx.x;
    for (int i = tid; i < 4096; i += 256) wlds[i] = Wf1[i];
    if (tid < 64) ssa[tid] = qbn_s(SA2, tid, invRa);
    __syncthreads();
    int grp = tid>>6, ch = tid&63;
    int agent = blockIdx.x*4 + grp;
    float best = -1.f, v0 = 0.f, v1 = 0.f;
    for (int e = 0; e < NEN; ++e) {
        size_t b = (size_t)(agent*NEN+e)*128;
        float x0 = XE[b+ch], x1 = XE[b+64+ch];
        float m2 = pair_m2(x0,x1);
        if (m2 > best) { best = m2; v0 = x0; v1 = x1; }
    }
    float sa = ssa[ch];
    for (int l = 0; l < NALY; ++l) {
        size_t b = (size_t)(agent*NALY+l)*128;
        float r0 = XAraw[b+ch], r1 = XAraw[b+64+ch];
        float u0 = r0/sa, u1 = r1/sa;
        float modf = sqrtf(pair_m2(u0,u1));
        float cff = modf / fmaxf(1.f, modf);
        float x0 = __fmul_rn(u0,cff), x1 = __fmul_rn(u1,cff);
        float m2 = pair_m2(x0,x1);
        if (m2 > best) { best = m2; v0 = x0; v1 = x1; }
    }
    v[grp][0][ch] = v0; v[grp][1][ch] = v1;
    __syncthreads();
    float a0 = 0.f, a1 = 0.f;
#pragma unroll
    for (int k = 0; k < 64; ++k) {
        float w = wlds[k*64+ch];
        a0 = fmaf(v[grp][0][k], w, a0);
        a1 = fmaf(v[grp][1][k], w, a1);
    }
    F1[(size_t)agent*128+ch] = a0; F1[(size_t)agent*128+64+ch] = a1;
    red[tid] = (double)a0*a0 + (double)a1*a1;
    __syncthreads();
    red_to_S(red, Sf1, blockIdx.x, tid);
}

// ---- vf finalize + SFb + VT = vf @ W1top for both imp chains. ----
__global__ __launch_bounds__(256) void k_vf_vtop(
    const float* __restrict__ F1, const double* __restrict__ Sf2,
    float* __restrict__ SFb,
    const float* __restrict__ Wie1, const float* __restrict__ Wia1,
    float* __restrict__ VTie, float* __restrict__ VTia, double invRows)
{
    __shared__ float wie[4096];
    __shared__ float wia[4096];
    __shared__ float vf[4][2][64];
    int tid = threadIdx.x;
    for (int i = tid; i < 4096; i += 256) { wie[i] = Wie1[i]; wia[i] = Wia1[i]; }
    int grp = tid>>6, ch = tid&63;
    int agent = blockIdx.x*4 + grp;
    float x0 = F1[(size_t)agent*128+ch], x1 = F1[(size_t)agent*128+64+ch];
    float s = qbn_s(Sf2, ch, invRows);
    float u0 = x0/s, u1 = x1/s;
    float mod = sqrtf(pair_m2(u0,u1));
    float cf = mod / fmaxf(1.f, mod);
    float y0 = __fmul_rn(u0,cf), y1 = __fmul_rn(u1,cf);
    vf[grp][0][ch] = y0; vf[grp][1][ch] = y1;
    SFb[(size_t)agent*64+ch] = pair_m2(y0,y1);
    __syncthreads();
    float a0=0.f,a1=0.f,b0=0.f,b1=0.f;
#pragma unroll
    for (int k = 0; k < 64; ++k) {
        float f0 = vf[grp][0][k], f1 = vf[grp][1][k];
        a0 = fmaf(f0, wie[k*64+ch], a0); a1 = fmaf(f1, wie[k*64+ch], a1);
        b0 = fmaf(f0, wia[k*64+ch], b0); b1 = fmaf(f1, wia[k*64+ch], b1);
    }
    VTie[(size_t)agent*128+ch] = a0; VTie[(size_t)agent*128+64+ch] = a1;
    VTia[(size_t)agent*128+ch] = b0; VTia[(size_t)agent*128+64+ch] = b1;
}

// ---- imp layer1: XI = VT + XE @ W1bot; 8 ents/block, 4 ents/thread. ----
__global__ __launch_bounds__(256) void k_imp1(
    const float* __restrict__ XE, const float* __restrict__ VT,
    const float* __restrict__ W1, float* __restrict__ XI, double* __restrict__ S1)
{
    __shared__ float wlds[4096];
    __shared__ float xt[1024];
    __shared__ double red[256];
    int tid = threadIdx.x;
    for (int i = tid; i < 4096; i += 256) wlds[i] = W1[4096 + i];
#pragma unroll
    for (int i = 0; i < 4; ++i)
        xt[tid + 256*i] = XE[(size_t)blockIdx.x*1024 + tid + 256*i];
    __syncthreads();
    int l = tid>>7, c = (tid>>6)&1, ch = tid&63;
    double lr = 0.0;
#pragma unroll
    for (int i = 0; i < 4; ++i) {
        int el = l + 2*i;
        int ent = blockIdx.x*8 + el;
        int agent = ent / NEN;
        const float* xr = &xt[el*128 + c*64];
        float acc = VT[(size_t)agent*128 + c*64 + ch];
#pragma unroll
        for (int k = 0; k < 64; ++k) acc = fmaf(xr[k], wlds[k*64+ch], acc);
        XI[(size_t)ent*128 + c*64 + ch] = acc;
        lr += (double)acc*(double)acc;
    }
    red[tid] = lr;
    __syncthreads();
    red_to_S(red, S1, blockIdx.x, tid);
}

// ---- imp layer3: 16 ents/block; one strided atomic per block. ----
__global__ __launch_bounds__(256) void k_imp3(
    const float* __restrict__ XI, const double* __restrict__ S2,
    const float* __restrict__ W3, float* __restrict__ Z, double* __restrict__ S3,
    double invRows)
{
    __shared__ float ss[64];
    __shared__ double red4[4];
    int tid = threadIdx.x; int grp = tid>>6, ch = tid&63;
    if (tid < 64) ss[tid] = qbn_s(S2, tid, invRows);
    __syncthreads();
    float s = ss[ch];
    double w3 = (double)W3[ch];
    double lr3 = 0.0;
#pragma unroll
    for (int i = 0; i < 4; ++i) {
        int ent = blockIdx.x*16 + grp + 4*i;
        float x0 = XI[(size_t)ent*128+ch], x1 = XI[(size_t)ent*128+64+ch];
        float u0 = x0/s, u1 = x1/s;
        float mod = sqrtf(pair_m2(u0,u1));
        float cf = mod / fmaxf(1.f, mod);
        double v0 = (double)__fmul_rn(u0,cf) * w3;
        double v1 = (double)__fmul_rn(u1,cf) * w3;
#pragma unroll
        for (int m = 1; m < 64; m <<= 1) { v0 += __shfl_xor(v0,m,64); v1 += __shfl_xor(v1,m,64); }
        if (ch == 0) {
            float z0 = (float)v0, z1 = (float)v1;
            Z[(size_t)ent*2] = z0; Z[(size_t)ent*2+1] = z1;
            lr3 += (double)z0*z0 + (double)z1*z1;
        }
    }
    if (ch == 0) red4[grp] = lr3;
    __syncthreads();
    if (tid == 0) atomicAdd(&S3[(blockIdx.x & 15)*8], red4[0]+red4[1]+red4[2]+red4[3]);
}

// ---- move_vec + oaq head + output cols 0..5. ----
__global__ __launch_bounds__(256) void k_final_small(
    const float* __restrict__ Zie, const float* __restrict__ Zia,
    const double* __restrict__ Sie3, const double* __restrict__ Sia3,
    const float* __restrict__ SFb,
    const float* __restrict__ Woa1, const float* __restrict__ boa1,
    const float* __restrict__ Woa2, const float* __restrict__ boa2,
    float* __restrict__ out, double invRows)
{
    __shared__ float sflds[4][64];
    int tid = threadIdx.x; int grp = tid>>6, ch = tid&63;
    int agent = blockIdx.x*4 + grp;
    float sie = sqrtf((float)(sum16sd8(Sie3)*invRows) + EPSF);
    float sia = sqrtf((float)(sum16sd8(Sia3)*invRows) + EPSF);
    double pv0 = 0.0, pv1 = 0.0;
    if (ch < NEN) {
        int ent = agent*NEN + ch;
        float z0 = Zie[(size_t)ent*2]/sie, z1 = Zie[(size_t)ent*2+1]/sie;
        float mod = sqrtf(pair_m2(z0,z1)); float cf = mod/fmaxf(1.f,mod);
        pv0 = (double)__fmul_rn(z0,cf); pv1 = (double)__fmul_rn(z1,cf);
        z0 = Zia[(size_t)ent*2]/sia; z1 = Zia[(size_t)ent*2+1]/sia;
        mod = sqrtf(pair_m2(z0,z1)); cf = mod/fmaxf(1.f,mod);
        pv0 += (double)__fmul_rn(z0,cf); pv1 += (double)__fmul_rn(z1,cf);
    }
#pragma unroll
    for (int m = 1; m < 64; m <<= 1) { pv0 += __shfl_xor(pv0,m,64); pv1 += __shfl_xor(pv1,m,64); }
    sflds[grp][ch] = SFb[(size_t)agent*64+ch];
    __syncthreads();
    double hd = (double)boa1[ch];
#pragma unroll
    for (int k = 0; k < 64; ++k) hd += (double)sflds[grp][k]*(double)Woa1[k*64+ch];
    float h = fmaxf((float)hd, 0.f);
    double q0 = (double)h*(double)Woa2[ch*3+0];
    double q1 = (double)h*(double)Woa2[ch*3+1];
    double q2 = (double)h*(double)Woa2[ch*3+2];
#pragma unroll
    for (int m = 1; m < 64; m <<= 1) { q0 += __shfl_xor(q0,m,64); q1 += __shfl_xor(q1,m,64); q2 += __shfl_xor(q2,m,64); }
    if (ch == 0) {
        float oaq0 = (float)(q0 + (double)boa2[0]);
        float oaq1 = (float)(q1 + (double)boa2[1]);
        float mmq  = (float)(q2 + (double)boa2[2]);
        float mv0 = (float)pv0, mv1 = (float)pv1;
        float* o = out + (size_t)agent*16;
        o[0] = oaq0; o[1] = oaq1;
        o[2] = mmq + mv1; o[3] = mmq - mv1;
        o[4] = mmq + mv0; o[5] = mmq - mv0;
    }
}

// ---- Attention MLP (128->128->64->1), f32 FMA, 16 rows/block. ----
__global__ __launch_bounds__(256) void k_attn(
    const float* __restrict__ SFb, const float* __restrict__ XE,
    const float* __restrict__ W1, const float* __restrict__ b1,
    const float* __restrict__ W2, const float* __restrict__ b2,
    const float* __restrict__ W3, const float* __restrict__ b3,
    float* __restrict__ out)
{
    __shared__ float atf[16][128];
    __shared__ float h1[16][128];
    __shared__ float h2[16][64];
    int tid = threadIdx.x;
    int row0 = blockIdx.x*16;
#pragma unroll
    for (int i = 0; i < 8; ++i) {
        int idx = tid + i*256; int r = idx>>7; int j = idx&127;
        int ent = row0 + r; int agent = ent/NEN;
        float v;
        if (j < 64) v = SFb[(size_t)agent*64+j];
        else {
            float x0 = XE[(size_t)ent*128 + (j-64)];
            float x1 = XE[(size_t)ent*128 + 64 + (j-64)];
            v = pair_m2(x0,x1);
        }
        atf[r][j] = v;
    }
    __syncthreads();
    {
        int j = tid & 127, rr = tid >> 7;
        float acc[8];
        float bb = b1[j];
#pragma unroll
        for (int r = 0; r < 8; ++r) acc[r] = bb;
        for (int k = 0; k < 128; ++k) {
            float w = W1[k*128+j];
#pragma unroll
            for (int r = 0; r < 8; ++r)
                acc[r] = fmaf(atf[rr*8+r][k], w, acc[r]);
        }
#pragma unroll
        for (int r = 0; r < 8; ++r) h1[rr*8+r][j] = fmaxf(acc[r], 0.f);
    }
    __syncthreads();
    {
        int j2 = tid & 63, rr2 = tid >> 6;
        float a[4];
        float bb = b2[j2];
#pragma unroll
        for (int r = 0; r < 4; ++r) a[r] = bb;
        for (int k = 0; k < 128; ++k) {
            float w = W2[k*64+j2];
#pragma unroll
            for (int r = 0; r < 4; ++r) a[r] = fmaf(h1[rr2*4+r][k], w, a[r]);
        }
#pragma unroll
        for (int r = 0; r < 4; ++r) h2[rr2*4+r][j2] = fmaxf(a[r], 0.f);
    }
    __syncthreads();
    {
        int r3 = tid >> 4, l3 = tid & 15;
        float s = h2[r3][l3]*W3[l3] + h2[r3][l3+16]*W3[l3+16]
                + h2[r3][l3+32]*W3[l3+32] + h2[r3][l3+48]*W3[l3+48];
#pragma unroll
        for (int m = 1; m < 16; m <<= 1) s += __shfl_xor(s, m, 64);
        if (l3 == 0) {
            int ent = row0 + r3; int agent = ent/NEN; int e = ent%NEN;
            out[(size_t)agent*16 + 6 + e] = s + b3[0];
        }
    }
}

extern "C" void kernel_launch(void* const* d_in, const int* in_sizes, int n_in,
                              void* d_out, int out_size, void* d_ws, size_t ws_size,
                              hipStream_t stream) {
    const float* own  = (const float*)d_in[0];
    const float* ef   = (const float*)d_in[1];
    const float* af   = (const float*)d_in[2];
    const float* W_e1 = (const float*)d_in[3];
    const float* W_e2 = (const float*)d_in[4];
    const float* W_a1 = (const float*)d_in[5];
    const float* W_a2 = (const float*)d_in[6];
    const float* W_f1 = (const float*)d_in[7];
    const float* W_f2 = (const float*)d_in[8];
    const float* W_ie1= (const float*)d_in[9];
    const float* W_ie2= (const float*)d_in[10];
    const float* W_ie3= (const float*)d_in[11];
    const float* W_ia1= (const float*)d_in[12];
    const float* W_ia2= (const float*)d_in[13];
    const float* W_ia3= (const float*)d_in[14];
    const float* W_oa1= (const float*)d_in[15];
    const float* b_oa1= (const float*)d_in[16];
    const float* W_oa2= (const float*)d_in[17];
    const float* b_oa2= (const float*)d_in[18];
    const float* W_at1= (const float*)d_in[19];
    const float* b_at1= (const float*)d_in[20];
    const float* W_at2= (const float*)d_in[21];
    const float* b_at2= (const float*)d_in[22];
    const float* W_at3= (const float*)d_in[23];
    const float* b_at3= (const float*)d_in[24];
    float* out = (float*)d_out;
    float* wsf = (float*)d_ws;
    double* Sd = (double*)d_ws;

    size_t o = (size_t)NDOUBLES*2;
    float*  X_E  = wsf + o; o += (size_t)NEE*128;
    float*  X_A  = wsf + o; o += (size_t)NAE*128;
    float*  F1   = wsf + o; o += (size_t)NAG*128;
    float*  SFb  = wsf + o; o += (size_t)NAG*64;
    float*  VT_IE = wsf + o; o += (size_t)NAG*128;
    float*  VT_IA = wsf + o; o += (size_t)NAG*128;
    float*  XI   = wsf + o; o += (size_t)NEE*128;
    float*  Z_IE = wsf + o; o += (size_t)NEE*2;
    float*  Z_IA = wsf + o; o += (size_t)NEE*2;

    double* S_E1 = Sd + DOFF_SE1;  double* S_E2 = Sd + DOFF_SE2;
    double* S_A1 = Sd + DOFF_SA1;  double* S_A2 = Sd + DOFF_SA2;
    double* S_F1 = Sd + DOFF_SF1;  double* S_F2 = Sd + DOFF_SF2;
    double* S_IE1= Sd + DOFF_SIE1; double* S_IE2= Sd + DOFF_SIE2;
    double* S_IA1= Sd + DOFF_SIA1; double* S_IA2= Sd + DOFF_SIA2;
    double* S_IE3= Sd + DOFF_SIE3; double* S_IA3= Sd + DOFF_SIA3;

    const double invRe = 1.0/(double)(NEE*2);
    const double invRa = 1.0/(double)(NAE*2);
    const double invRf = 1.0/(double)(NAG*2);

    hipMemsetAsync(Sd, 0, (size_t)NDOUBLES*sizeof(double), stream);

    k_build_pair<<<NEE/8, 256, 0, stream>>>(ef, own, W_e1, X_E, S_E1, NEN);
    k_build_pair<<<NAE/8, 256, 0, stream>>>(af, own, W_a1, X_A, S_A1, NALY);
    k_pair_layer<<<NEE/16, 256, 0, stream>>>(X_E, S_E1, S_E2, W_e2, invRe);
    k_pair_layer<<<NAE/16, 256, 0, stream>>>(X_A, S_A1, S_A2, W_a2, invRa);
    k_finalize_pair<<<NEE*128/256, 256, 0, stream>>>(X_E, S_E2, invRe);
    k_pool_f1<<<NAG/4, 256, 0, stream>>>(X_E, X_A, S_A2, invRa, W_f1, F1, S_F1);
    k_pair_layer<<<NAG/16, 256, 0, stream>>>(F1, S_F1, S_F2, W_f2, invRf);
    k_vf_vtop<<<NAG/4, 256, 0, stream>>>(F1, S_F2, SFb, W_ie1, W_ia1, VT_IE, VT_IA, invRf);
    // e-importance chain
    k_imp1<<<NEE/8, 256, 0, stream>>>(X_E, VT_IE, W_ie1, XI, S_IE1);
    k_pair_layer<<<NEE/16, 256, 0, stream>>>(XI, S_IE1, S_IE2, W_ie2, invRe);
    k_imp3<<<NEE/16, 256, 0, stream>>>(XI, S_IE2, W_ie3, Z_IE, S_IE3, invRe);
    // a-importance chain (same cat input; XI reused)
    k_imp1<<<NEE/8, 256, 0, stream>>>(X_E, VT_IA, W_ia1, XI, S_IA1);
    k_pair_layer<<<NEE/16, 256, 0, stream>>>(XI, S_IA1, S_IA2, W_ia2, invRe);
    k_imp3<<<NEE/16, 256, 0, stream>>>(XI, S_IA2, W_ia3, Z_IA, S_IA3, invRe);

    k_final_small<<<NAG/4, 256, 0, stream>>>(Z_IE, Z_IA, S_IE3, S_IA3, SFb,
                                             W_oa1, b_oa1, W_oa2, b_oa2, out, invRe);
    k_attn<<<NEE/16, 256, 0, stream>>>(SFb, X_E, W_at1, b_at1, W_at2, b_at2,
                                       W_at3, b_at3, out);
}

// Round 13
// 735.573 us; speedup vs baseline: 2.2084x; 1.0890x over previous
//
#include <hip/hip_runtime.h>
#include <math.h>

// Problem constants
#define BATCH 1024
#define NA 10
#define NEN 10
#define NALY 9
#define NAG (BATCH*NA)          // 10240
#define NEE (NAG*NEN)           // 102400
#define NAE (NAG*NALY)          // 92160
#define EPSF 1e-5f

// f64 replicated qbn-sum buffers (16 replicas), at start of ws (double units)
#define DOFF_SE1 0
#define DOFF_SE2 1024
#define DOFF_SA1 2048
#define DOFF_SA2 3072
#define DOFF_SF1 4096
#define DOFF_SF2 5120
#define DOFF_SIE1 6144
#define DOFF_SIE2 7168
#define DOFF_SIA1 8192
#define DOFF_SIA2 9216
#define DOFF_SIE3 10240   // 16 replicas x stride 8 (one cache line each)
#define DOFF_SIA3 10368   // 16 replicas x stride 8
#define NDOUBLES 16384

__device__ __forceinline__ double sum16vd(const double* __restrict__ S, int ch) {
    double s = 0.0;
#pragma unroll
    for (int r = 0; r < 16; ++r) s += S[r*64 + ch];
    return s;
}
__device__ __forceinline__ double sum16sd8(const double* __restrict__ S) {
    double s = 0.0;
#pragma unroll
    for (int r = 0; r < 16; ++r) s += S[r*8];
    return s;
}
// qbn scale: s = fl32(sqrt(fl32(exact_mean) + eps))
__device__ __forceinline__ float qbn_s(const double* __restrict__ S, int ch, double invRows) {
    float m = (float)(sum16vd(S, ch)*invRows);
    return sqrtf(m + EPSF);
}
__device__ __forceinline__ void red_to_S(const double* red, double* S, int bid, int tid) {
    if (tid < 64) {
        double v = red[tid] + red[tid+64] + red[tid+128] + red[tid+192];
        atomicAdd(&S[(bid & 15)*64 + tid], v);
    }
}
// np-lattice pair mod^2: fl(fl(x0^2)+fl(x1^2)) (no FMA contraction)
__device__ __forceinline__ float pair_m2(float x0, float x1) {
    return __fadd_rn(__fmul_rn(x0,x0), __fmul_rn(x1,x1));
}

// ---- build_vec + layer1 GEMM; 8 ents/block, 4 ents/thread. Per-output
//      FP sequence identical to R10 (REVERSED k, FROZEN — feeds pool). ----
__global__ __launch_bounds__(256) void k_build_pair(
    const float* __restrict__ feats, const float* __restrict__ own,
    const float* __restrict__ W1, float* __restrict__ X,
    double* __restrict__ S1, int nEntPerAgent)
{
    __shared__ float wlds[19*64];
    __shared__ float g[8][19];
    __shared__ float pxy[8][2];
    __shared__ double red[256];
    int tid = threadIdx.x;
    for (int i = tid; i < 19*64; i += 256) wlds[i] = W1[i];
    if (tid < 152) {
        int el = tid / 19, chg = tid % 19;
        int ent = blockIdx.x*8 + el;
        const float* f = feats + (size_t)ent*9;
        int agent = ent / nEntPerAgent;
        float px = f[2], py = f[3];
        float pm = sqrtf(__fadd_rn(__fmul_rn(px,px), __fmul_rn(py,py)));
        float val;
        if (chg == 0) val = 1.f;
        else if (chg < 8) {
            int j = chg - 1;
            int fi = (j < 2) ? j : (j + 2);
            float o = f[fi];
            float om = sqrtf(__fmul_rn(__fmul_rn(2.0f,o),o));
            val = (pm == 0.f) ? 0.f : __fdiv_rn(om, pm);
        } else {
            float o = own[(size_t)agent*11 + (chg-8)];
            float t = __fmul_rn(o,o);
            float om = sqrtf(__fadd_rn(t,t));
            val = (pm == 0.f) ? 0.f : __fdiv_rn(om, pm);
        }
        g[el][chg] = val;
        if (chg == 0) { pxy[el][0] = px; pxy[el][1] = py; }
    }
    __syncthreads();
    int l = tid >> 7, c = (tid >> 6) & 1, ch = tid & 63;
    double lr = 0.0;
#pragma unroll
    for (int i = 0; i < 4; ++i) {
        int el = l + 2*i;
        int ent = blockIdx.x*8 + el;
        float pc = pxy[el][c];
        float acc = 0.f;
#pragma unroll
        for (int k = 18; k >= 0; --k) {            // REVERSED k (frozen)
            float ev = __fmul_rn(pc, g[el][k]);
            acc = fmaf(ev, wlds[k*64+ch], acc);
        }
        X[(size_t)ent*128 + c*64 + ch] = acc;
        lr += (double)acc * (double)acc;
    }
    red[tid] = lr;
    __syncthreads();
    red_to_S(red, S1, blockIdx.x, tid);
}

// ---- pair layer: qbn + qrelu + 64x64 GEMM; 16 rows/block, ch-vectorized
//      (4 ch/thread). Per-output fmaf chain identical to R10 (REVERSED k). --
__global__ __launch_bounds__(256) void k_pair_layer(
    float* __restrict__ X, const double* __restrict__ Sin, double* __restrict__ Sout,
    const float* __restrict__ W, double invRows)
{
    __shared__ float wlds[4096];
    __shared__ float ybuf[16][132];   // [row][2*ch + p], padded
    __shared__ float ss[64];
    __shared__ double dred[16][64];
    int tid = threadIdx.x;
    for (int i = tid; i < 4096; i += 256) wlds[i] = W[i];
    if (tid < 64) ss[tid] = qbn_s(Sin, tid, invRows);
    __syncthreads();
    int rl = tid >> 4;
    int ch0 = (tid & 15) * 4;
    size_t row = (size_t)blockIdx.x*16 + rl;
    float4 xv0 = *(const float4*)&X[row*128 + ch0];
    float4 xv1 = *(const float4*)&X[row*128 + 64 + ch0];
    {
        float xs0[4] = {xv0.x,xv0.y,xv0.z,xv0.w};
        float xs1[4] = {xv1.x,xv1.y,xv1.z,xv1.w};
        float y0[4], y1[4];
#pragma unroll
        for (int i = 0; i < 4; ++i) {
            float s = ss[ch0+i];
            float u0 = xs0[i]/s, u1 = xs1[i]/s;
            float mod = sqrtf(pair_m2(u0,u1));
            float cf = mod / fmaxf(1.f, mod);
            y0[i] = __fmul_rn(u0,cf);
            y1[i] = __fmul_rn(u1,cf);
        }
        *(float4*)&ybuf[rl][2*ch0]     = make_float4(y0[0],y1[0],y0[1],y1[1]);
        *(float4*)&ybuf[rl][2*ch0 + 4] = make_float4(y0[2],y1[2],y0[3],y1[3]);
    }
    __syncthreads();
    float a0[4] = {0.f,0.f,0.f,0.f};
    float a1[4] = {0.f,0.f,0.f,0.f};
#pragma unroll
    for (int k = 63; k >= 1; k -= 2) {           // REVERSED k, unroll 2
        float4 wk  = *(const float4*)&wlds[k*64 + ch0];
        float4 wk1 = *(const float4*)&wlds[(k-1)*64 + ch0];
        float4 y4  = *(const float4*)&ybuf[rl][2*k - 2]; // (k-1,p0)(k-1,p1)(k,p0)(k,p1)
        float wkv[4]  = {wk.x,wk.y,wk.z,wk.w};
        float wk1v[4] = {wk1.x,wk1.y,wk1.z,wk1.w};
#pragma unroll
        for (int i = 0; i < 4; ++i) {
            a0[i] = fmaf(y4.z, wkv[i], a0[i]);
            a1[i] = fmaf(y4.w, wkv[i], a1[i]);
        }
#pragma unroll
        for (int i = 0; i < 4; ++i) {
            a0[i] = fmaf(y4.x, wk1v[i], a0[i]);
            a1[i] = fmaf(y4.y, wk1v[i], a1[i]);
        }
    }
    *(float4*)&X[row*128 + ch0]      = make_float4(a0[0],a0[1],a0[2],a0[3]);
    *(float4*)&X[row*128 + 64 + ch0] = make_float4(a1[0],a1[1],a1[2],a1[3]);
#pragma unroll
    for (int i = 0; i < 4; ++i)
        dred[rl][ch0+i] = (double)a0[i]*a0[i] + (double)a1[i]*a1[i];
    __syncthreads();
    if (tid < 64) {
        double v = 0.0;
#pragma unroll
        for (int r = 0; r < 16; ++r) v += dred[r][tid];
        atomicAdd(&Sout[(blockIdx.x & 15)*64 + tid], v);
    }
}

// ---- Finalize (E only): y = qrelu(qbn(x)), in place, b128. Ops identical. --
__global__ __launch_bounds__(256) void k_finalize_pair(
    float* __restrict__ X, const double* __restrict__ S2, double invRows)
{
    __shared__ float ss[64];
    if (threadIdx.x < 64) ss[threadIdx.x] = qbn_s(S2, threadIdx.x, invRows);
    int t = blockIdx.x*256 + threadIdx.x;
    int rl = t >> 4;              // (ent*2 + c) row index
    int ch0 = (t & 15) * 4;
    size_t base    = (size_t)rl*64 + ch0;
    size_t partner = (size_t)(rl ^ 1)*64 + ch0;
    float4 xv  = *(const float4*)&X[base];
    float4 xov = *(const float4*)&X[partner];
    __syncthreads();
    float xs[4]  = {xv.x,xv.y,xv.z,xv.w};
    float xos[4] = {xov.x,xov.y,xov.z,xov.w};
    float r[4];
#pragma unroll
    for (int i = 0; i < 4; ++i) {
        float s = ss[ch0+i];
        float u  = xs[i]/s;
        float uo = xos[i]/s;
        int c = rl & 1;
        float u0 = (c==0) ? u : uo, u1 = (c==0) ? uo : u;
        float mod = sqrtf(pair_m2(u0,u1));
        float cf = mod / fmaxf(1.f, mod);
        r[i] = __fmul_rn(u, cf);
    }
    *(float4*)&X[base] = make_float4(r[0],r[1],r[2],r[3]);
}

// ---- Pool + f1 GEMM, ally finalize fused (identical op sequence). ----
__global__ __launch_bounds__(256) void k_pool_f1(
    const float* __restrict__ XE, const float* __restrict__ XAraw,
    const double* __restrict__ SA2, double invRa,
    const float* __restrict__ Wf1, float* __restrict__ F1, double* __restrict__ Sf1)
{
    __shared__ float wlds[4096];
    __shared__ float v[4][2][64];
    __shared__ float ssa[64];
    __shared__ double red[256];
    int tid = threadIdx.x;
    for (int i = tid; i < 4096; i += 256) wlds[i] = Wf1[i];
    if (tid < 64) ssa[tid] = qbn_s(SA2, tid, invRa);
    __syncthreads();
    int grp = tid>>6, ch = tid&63;
    int agent = blockIdx.x*4 + grp;
    float best = -1.f, v0 = 0.f, v1 = 0.f;
    for (int e = 0; e < NEN; ++e) {
        size_t b = (size_t)(agent*NEN+e)*128;
        float x0 = XE[b+ch], x1 = XE[b+64+ch];
        float m2 = pair_m2(x0,x1);
        if (m2 > best) { best = m2; v0 = x0; v1 = x1; }
    }
    float sa = ssa[ch];
    for (int l = 0; l < NALY; ++l) {
        size_t b = (size_t)(agent*NALY+l)*128;
        float r0 = XAraw[b+ch], r1 = XAraw[b+64+ch];
        float u0 = r0/sa, u1 = r1/sa;
        float modf = sqrtf(pair_m2(u0,u1));
        float cff = modf / fmaxf(1.f, modf);
        float x0 = __fmul_rn(u0,cff), x1 = __fmul_rn(u1,cff);
        float m2 = pair_m2(x0,x1);
        if (m2 > best) { best = m2; v0 = x0; v1 = x1; }
    }
    v[grp][0][ch] = v0; v[grp][1][ch] = v1;
    __syncthreads();
    float a0 = 0.f, a1 = 0.f;
#pragma unroll
    for (int k = 0; k < 64; ++k) {
        float w = wlds[k*64+ch];
        a0 = fmaf(v[grp][0][k], w, a0);
        a1 = fmaf(v[grp][1][k], w, a1);
    }
    F1[(size_t)agent*128+ch] = a0; F1[(size_t)agent*128+64+ch] = a1;
    red[tid] = (double)a0*a0 + (double)a1*a1;
    __syncthreads();
    red_to_S(red, Sf1, blockIdx.x, tid);
}

// ---- vf finalize + SFb + VT = vf @ W1top for both imp chains. ----
__global__ __launch_bounds__(256) void k_vf_vtop(
    const float* __restrict__ F1, const double* __restrict__ Sf2,
    float* __restrict__ SFb,
    const float* __restrict__ Wie1, const float* __restrict__ Wia1,
    float* __restrict__ VTie, float* __restrict__ VTia, double invRows)
{
    __shared__ float wie[4096];
    __shared__ float wia[4096];
    __shared__ float vf[4][2][64];
    int tid = threadIdx.x;
    for (int i = tid; i < 4096; i += 256) { wie[i] = Wie1[i]; wia[i] = Wia1[i]; }
    int grp = tid>>6, ch = tid&63;
    int agent = blockIdx.x*4 + grp;
    float x0 = F1[(size_t)agent*128+ch], x1 = F1[(size_t)agent*128+64+ch];
    float s = qbn_s(Sf2, ch, invRows);
    float u0 = x0/s, u1 = x1/s;
    float mod = sqrtf(pair_m2(u0,u1));
    float cf = mod / fmaxf(1.f, mod);
    float y0 = __fmul_rn(u0,cf), y1 = __fmul_rn(u1,cf);
    vf[grp][0][ch] = y0; vf[grp][1][ch] = y1;
    SFb[(size_t)agent*64+ch] = pair_m2(y0,y1);
    __syncthreads();
    float a0=0.f,a1=0.f,b0=0.f,b1=0.f;
#pragma unroll
    for (int k = 0; k < 64; ++k) {
        float f0 = vf[grp][0][k], f1 = vf[grp][1][k];
        a0 = fmaf(f0, wie[k*64+ch], a0); a1 = fmaf(f1, wie[k*64+ch], a1);
        b0 = fmaf(f0, wia[k*64+ch], b0); b1 = fmaf(f1, wia[k*64+ch], b1);
    }
    VTie[(size_t)agent*128+ch] = a0; VTie[(size_t)agent*128+64+ch] = a1;
    VTia[(size_t)agent*128+ch] = b0; VTia[(size_t)agent*128+64+ch] = b1;
}

// ---- imp layer1: XI = VT + XE @ W1bot; 8 ents/block, ch-vectorized. ----
__global__ __launch_bounds__(256) void k_imp1(
    const float* __restrict__ XE, const float* __restrict__ VT,
    const float* __restrict__ W1, float* __restrict__ XI, double* __restrict__ S1)
{
    __shared__ float wlds[4096];
    __shared__ float xt[16][68];      // 16 rows=(ent,c) x 64 k, padded
    __shared__ double dred[16][64];
    int tid = threadIdx.x;
    for (int i = tid; i < 4096; i += 256) wlds[i] = W1[4096 + i];
    {
        int r = tid >> 4;             // 256 float4 = 16 rows x 16 quads
        int kq = (tid & 15) * 4;
        float4 t4 = *(const float4*)&XE[(size_t)blockIdx.x*1024 + tid*4];
        *(float4*)&xt[r][kq] = t4;
    }
    __syncthreads();
    int rl = tid >> 4;
    int ch0 = (tid & 15) * 4;
    int ent = blockIdx.x*8 + (rl >> 1);
    int c = rl & 1;
    int agent = ent / NEN;
    float4 vt = *(const float4*)&VT[(size_t)agent*128 + c*64 + ch0];
    float acc[4] = {vt.x, vt.y, vt.z, vt.w};
#pragma unroll
    for (int k = 0; k < 64; k += 4) {
        float4 x4 = *(const float4*)&xt[rl][k];
        float xk[4] = {x4.x, x4.y, x4.z, x4.w};
#pragma unroll
        for (int kk = 0; kk < 4; ++kk) {
            float4 w4 = *(const float4*)&wlds[(k+kk)*64 + ch0];
            acc[0] = fmaf(xk[kk], w4.x, acc[0]);
            acc[1] = fmaf(xk[kk], w4.y, acc[1]);
            acc[2] = fmaf(xk[kk], w4.z, acc[2]);
            acc[3] = fmaf(xk[kk], w4.w, acc[3]);
        }
    }
    *(float4*)&XI[(size_t)ent*128 + c*64 + ch0] = make_float4(acc[0],acc[1],acc[2],acc[3]);
#pragma unroll
    for (int i = 0; i < 4; ++i)
        dred[rl][ch0+i] = (double)acc[i]*acc[i];
    __syncthreads();
    if (tid < 64) {
        double v = 0.0;
#pragma unroll
        for (int r = 0; r < 16; ++r) v += dred[r][tid];
        atomicAdd(&S1[(blockIdx.x & 15)*64 + tid], v);
    }
}

// ---- imp layer3: 16 ents/block; one strided atomic per block. ----
__global__ __launch_bounds__(256) void k_imp3(
    const float* __restrict__ XI, const double* __restrict__ S2,
    const float* __restrict__ W3, float* __restrict__ Z, double* __restrict__ S3,
    double invRows)
{
    __shared__ float ss[64];
    __shared__ double red4[4];
    int tid = threadIdx.x; int grp = tid>>6, ch = tid&63;
    if (tid < 64) ss[tid] = qbn_s(S2, tid, invRows);
    __syncthreads();
    float s = ss[ch];
    double w3 = (double)W3[ch];
    double lr3 = 0.0;
#pragma unroll
    for (int i = 0; i < 4; ++i) {
        int ent = blockIdx.x*16 + grp + 4*i;
        float x0 = XI[(size_t)ent*128+ch], x1 = XI[(size_t)ent*128+64+ch];
        float u0 = x0/s, u1 = x1/s;
        float mod = sqrtf(pair_m2(u0,u1));
        float cf = mod / fmaxf(1.f, mod);
        double v0 = (double)__fmul_rn(u0,cf) * w3;
        double v1 = (double)__fmul_rn(u1,cf) * w3;
#pragma unroll
        for (int m = 1; m < 64; m <<= 1) { v0 += __shfl_xor(v0,m,64); v1 += __shfl_xor(v1,m,64); }
        if (ch == 0) {
            float z0 = (float)v0, z1 = (float)v1;
            Z[(size_t)ent*2] = z0; Z[(size_t)ent*2+1] = z1;
            lr3 += (double)z0*z0 + (double)z1*z1;
        }
    }
    if (ch == 0) red4[grp] = lr3;
    __syncthreads();
    if (tid == 0) atomicAdd(&S3[(blockIdx.x & 15)*8], red4[0]+red4[1]+red4[2]+red4[3]);
}

// ---- move_vec + oaq head + output cols 0..5. ----
__global__ __launch_bounds__(256) void k_final_small(
    const float* __restrict__ Zie, const float* __restrict__ Zia,
    const double* __restrict__ Sie3, const double* __restrict__ Sia3,
    const float* __restrict__ SFb,
    const float* __restrict__ Woa1, const float* __restrict__ boa1,
    const float* __restrict__ Woa2, const float* __restrict__ boa2,
    float* __restrict__ out, double invRows)
{
    __shared__ float sflds[4][64];
    int tid = threadIdx.x; int grp = tid>>6, ch = tid&63;
    int agent = blockIdx.x*4 + grp;
    float sie = sqrtf((float)(sum16sd8(Sie3)*invRows) + EPSF);
    float sia = sqrtf((float)(sum16sd8(Sia3)*invRows) + EPSF);
    double pv0 = 0.0, pv1 = 0.0;
    if (ch < NEN) {
        int ent = agent*NEN + ch;
        float z0 = Zie[(size_t)ent*2]/sie, z1 = Zie[(size_t)ent*2+1]/sie;
        float mod = sqrtf(pair_m2(z0,z1)); float cf = mod/fmaxf(1.f,mod);
        pv0 = (double)__fmul_rn(z0,cf); pv1 = (double)__fmul_rn(z1,cf);
        z0 = Zia[(size_t)ent*2]/sia; z1 = Zia[(size_t)ent*2+1]/sia;
        mod = sqrtf(pair_m2(z0,z1)); cf = mod/fmaxf(1.f,mod);
        pv0 += (double)__fmul_rn(z0,cf); pv1 += (double)__fmul_rn(z1,cf);
    }
#pragma unroll
    for (int m = 1; m < 64; m <<= 1) { pv0 += __shfl_xor(pv0,m,64); pv1 += __shfl_xor(pv1,m,64); }
    sflds[grp][ch] = SFb[(size_t)agent*64+ch];
    __syncthreads();
    double hd = (double)boa1[ch];
#pragma unroll
    for (int k = 0; k < 64; ++k) hd += (double)sflds[grp][k]*(double)Woa1[k*64+ch];
    float h = fmaxf((float)hd, 0.f);
    double q0 = (double)h*(double)Woa2[ch*3+0];
    double q1 = (double)h*(double)Woa2[ch*3+1];
    double q2 = (double)h*(double)Woa2[ch*3+2];
#pragma unroll
    for (int m = 1; m < 64; m <<= 1) { q0 += __shfl_xor(q0,m,64); q1 += __shfl_xor(q1,m,64); q2 += __shfl_xor(q2,m,64); }
    if (ch == 0) {
        float oaq0 = (float)(q0 + (double)boa2[0]);
        float oaq1 = (float)(q1 + (double)boa2[1]);
        float mmq  = (float)(q2 + (double)boa2[2]);
        float mv0 = (float)pv0, mv1 = (float)pv1;
        float* o = out + (size_t)agent*16;
        o[0] = oaq0; o[1] = oaq1;
        o[2] = mmq + mv1; o[3] = mmq - mv1;
        o[4] = mmq + mv0; o[5] = mmq - mv0;
    }
}

// ---- Attention MLP (128->128->64->1), f32, 32 rows/block, 4x4 reg tiles. --
__global__ __launch_bounds__(256) void k_attn(
    const float* __restrict__ SFb, const float* __restrict__ XE,
    const float* __restrict__ W1, const float* __restrict__ b1,
    const float* __restrict__ W2, const float* __restrict__ b2,
    const float* __restrict__ W3, const float* __restrict__ b3,
    float* __restrict__ out)
{
    __shared__ float atf[32][132];
    __shared__ float h1[32][132];
    __shared__ float h2[32][68];
    int tid = threadIdx.x;
    int row0 = blockIdx.x*32;
#pragma unroll
    for (int i = 0; i < 16; ++i) {
        int idx = tid + i*256; int r = idx>>7; int j = idx&127;
        int ent = row0 + r; int agent = ent/NEN;
        float v;
        if (j < 64) v = SFb[(size_t)agent*64+j];
        else {
            float x0 = XE[(size_t)ent*128 + (j-64)];
            float x1 = XE[(size_t)ent*128 + 64 + (j-64)];
            v = pair_m2(x0,x1);
        }
        atf[r][j] = v;
    }
    __syncthreads();
    {   // layer1: 32 rows x 128 cols, k=128, tile 4 rows x 4 cols
        int rg = tid >> 5;            // 0..7 -> rows rg*4..+3
        int j0 = (tid & 31) * 4;
        float4 bb = *(const float4*)&b1[j0];
        float acc[4][4];
#pragma unroll
        for (int r = 0; r < 4; ++r) {
            acc[r][0]=bb.x; acc[r][1]=bb.y; acc[r][2]=bb.z; acc[r][3]=bb.w;
        }
        for (int k = 0; k < 128; k += 4) {
            float4 a4[4];
#pragma unroll
            for (int r = 0; r < 4; ++r) a4[r] = *(const float4*)&atf[rg*4+r][k];
#pragma unroll
            for (int kk = 0; kk < 4; ++kk) {
                float4 w4 = *(const float4*)&W1[(k+kk)*128 + j0];
                float av[4] = { ((const float*)&a4[0])[kk], ((const float*)&a4[1])[kk],
                                ((const float*)&a4[2])[kk], ((const float*)&a4[3])[kk] };
#pragma unroll
                for (int r = 0; r < 4; ++r) {
                    acc[r][0] = fmaf(av[r], w4.x, acc[r][0]);
                    acc[r][1] = fmaf(av[r], w4.y, acc[r][1]);
                    acc[r][2] = fmaf(av[r], w4.z, acc[r][2]);
                    acc[r][3] = fmaf(av[r], w4.w, acc[r][3]);
                }
            }
        }
#pragma unroll
        for (int r = 0; r < 4; ++r)
            *(float4*)&h1[rg*4+r][j0] = make_float4(fmaxf(acc[r][0],0.f), fmaxf(acc[r][1],0.f),
                                                   fmaxf(acc[r][2],0.f), fmaxf(acc[r][3],0.f));
    }
    __syncthreads();
    {   // layer2: 32 rows x 64 cols, k=128, tile 2 rows x 4 cols
        int rg = tid >> 4;            // 0..15 -> rows rg*2..+1
        int j0 = (tid & 15) * 4;
        float4 bb = *(const float4*)&b2[j0];
        float acc[2][4];
#pragma unroll
        for (int r = 0; r < 2; ++r) {
            acc[r][0]=bb.x; acc[r][1]=bb.y; acc[r][2]=bb.z; acc[r][3]=bb.w;
        }
        for (int k = 0; k < 128; k += 4) {
            float4 p0 = *(const float4*)&h1[rg*2][k];
            float4 p1 = *(const float4*)&h1[rg*2+1][k];
            float pv0[4] = {p0.x,p0.y,p0.z,p0.w};
            float pv1[4] = {p1.x,p1.y,p1.z,p1.w};
#pragma unroll
            for (int kk = 0; kk < 4; ++kk) {
                float4 w4 = *(const float4*)&W2[(k+kk)*64 + j0];
                acc[0][0] = fmaf(pv0[kk], w4.x, acc[0][0]);
                acc[0][1] = fmaf(pv0[kk], w4.y, acc[0][1]);
                acc[0][2] = fmaf(pv0[kk], w4.z, acc[0][2]);
                acc[0][3] = fmaf(pv0[kk], w4.w, acc[0][3]);
                acc[1][0] = fmaf(pv1[kk], w4.x, acc[1][0]);
                acc[1][1] = fmaf(pv1[kk], w4.y, acc[1][1]);
                acc[1][2] = fmaf(pv1[kk], w4.z, acc[1][2]);
                acc[1][3] = fmaf(pv1[kk], w4.w, acc[1][3]);
            }
        }
#pragma unroll
        for (int r = 0; r < 2; ++r)
            *(float4*)&h2[rg*2+r][j0] = make_float4(fmaxf(acc[r][0],0.f), fmaxf(acc[r][1],0.f),
                                                   fmaxf(acc[r][2],0.f), fmaxf(acc[r][3],0.f));
    }
    __syncthreads();
    {   // layer3: 32 rows, 8 lanes/row
        int r3 = tid >> 3, l3 = tid & 7;
        float s = 0.f;
#pragma unroll
        for (int q = 0; q < 8; ++q) s = fmaf(h2[r3][l3 + 8*q], W3[l3 + 8*q], s);
#pragma unroll
        for (int m = 1; m < 8; m <<= 1) s += __shfl_xor(s, m, 64);
        if (l3 == 0) {
            int ent = row0 + r3; int agent = ent/NEN; int e = ent%NEN;
            out[(size_t)agent*16 + 6 + e] = s + b3[0];
        }
    }
}

extern "C" void kernel_launch(void* const* d_in, const int* in_sizes, int n_in,
                              void* d_out, int out_size, void* d_ws, size_t ws_size,
                              hipStream_t stream) {
    const float* own  = (const float*)d_in[0];
    const float* ef   = (const float*)d_in[1];
    const float* af   = (const float*)d_in[2];
    const float* W_e1 = (const float*)d_in[3];
    const float* W_e2 = (const float*)d_in[4];
    const float* W_a1 = (const float*)d_in[5];
    const float* W_a2 = (const float*)d_in[6];
    const float* W_f1 = (const float*)d_in[7];
    const float* W_f2 = (const float*)d_in[8];
    const float* W_ie1= (const float*)d_in[9];
    const float* W_ie2= (const float*)d_in[10];
    const float* W_ie3= (const float*)d_in[11];
    const float* W_ia1= (const float*)d_in[12];
    const float* W_ia2= (const float*)d_in[13];
    const float* W_ia3= (const float*)d_in[14];
    const float* W_oa1= (const float*)d_in[15];
    const float* b_oa1= (const float*)d_in[16];
    const float* W_oa2= (const float*)d_in[17];
    const float* b_oa2= (const float*)d_in[18];
    const float* W_at1= (const float*)d_in[19];
    const float* b_at1= (const float*)d_in[20];
    const float* W_at2= (const float*)d_in[21];
    const float* b_at2= (const float*)d_in[22];
    const float* W_at3= (const float*)d_in[23];
    const float* b_at3= (const float*)d_in[24];
    float* out = (float*)d_out;
    float* wsf = (float*)d_ws;
    double* Sd = (double*)d_ws;

    size_t o = (size_t)NDOUBLES*2;
    float*  X_E  = wsf + o; o += (size_t)NEE*128;
    float*  X_A  = wsf + o; o += (size_t)NAE*128;
    float*  F1   = wsf + o; o += (size_t)NAG*128;
    float*  SFb  = wsf + o; o += (size_t)NAG*64;
    float*  VT_IE = wsf + o; o += (size_t)NAG*128;
    float*  VT_IA = wsf + o; o += (size_t)NAG*128;
    float*  XI   = wsf + o; o += (size_t)NEE*128;
    float*  Z_IE = wsf + o; o += (size_t)NEE*2;
    float*  Z_IA = wsf + o; o += (size_t)NEE*2;

    double* S_E1 = Sd + DOFF_SE1;  double* S_E2 = Sd + DOFF_SE2;
    double* S_A1 = Sd + DOFF_SA1;  double* S_A2 = Sd + DOFF_SA2;
    double* S_F1 = Sd + DOFF_SF1;  double* S_F2 = Sd + DOFF_SF2;
    double* S_IE1= Sd + DOFF_SIE1; double* S_IE2= Sd + DOFF_SIE2;
    double* S_IA1= Sd + DOFF_SIA1; double* S_IA2= Sd + DOFF_SIA2;
    double* S_IE3= Sd + DOFF_SIE3; double* S_IA3= Sd + DOFF_SIA3;

    const double invRe = 1.0/(double)(NEE*2);
    const double invRa = 1.0/(double)(NAE*2);
    const double invRf = 1.0/(double)(NAG*2);

    hipMemsetAsync(Sd, 0, (size_t)NDOUBLES*sizeof(double), stream);

    k_build_pair<<<NEE/8, 256, 0, stream>>>(ef, own, W_e1, X_E, S_E1, NEN);
    k_build_pair<<<NAE/8, 256, 0, stream>>>(af, own, W_a1, X_A, S_A1, NALY);
    k_pair_layer<<<NEE/16, 256, 0, stream>>>(X_E, S_E1, S_E2, W_e2, invRe);
    k_pair_layer<<<NAE/16, 256, 0, stream>>>(X_A, S_A1, S_A2, W_a2, invRa);
    k_finalize_pair<<<NEE*32/256, 256, 0, stream>>>(X_E, S_E2, invRe);
    k_pool_f1<<<NAG/4, 256, 0, stream>>>(X_E, X_A, S_A2, invRa, W_f1, F1, S_F1);
    k_pair_layer<<<NAG/16, 256, 0, stream>>>(F1, S_F1, S_F2, W_f2, invRf);
    k_vf_vtop<<<NAG/4, 256, 0, stream>>>(F1, S_F2, SFb, W_ie1, W_ia1, VT_IE, VT_IA, invRf);
    // e-importance chain
    k_imp1<<<NEE/8, 256, 0, stream>>>(X_E, VT_IE, W_ie1, XI, S_IE1);
    k_pair_layer<<<NEE/16, 256, 0, stream>>>(XI, S_IE1, S_IE2, W_ie2, invRe);
    k_imp3<<<NEE/16, 256, 0, stream>>>(XI, S_IE2, W_ie3, Z_IE, S_IE3, invRe);
    // a-importance chain (same cat input; XI reused)
    k_imp1<<<NEE/8, 256, 0, stream>>>(X_E, VT_IA, W_ia1, XI, S_IA1);
    k_pair_layer<<<NEE/16, 256, 0, stream>>>(XI, S_IA1, S_IA2, W_ia2, invRe);
    k_imp3<<<NEE/16, 256, 0, stream>>>(XI, S_IA2, W_ia3, Z_IA, S_IA3, invRe);

    k_final_small<<<NAG/4, 256, 0, stream>>>(Z_IE, Z_IA, S_IE3, S_IA3, SFb,
                                             W_oa1, b_oa1, W_oa2, b_oa2, out, invRe);
    k_attn<<<NEE/32, 256, 0, stream>>>(SFb, X_E, W_at1, b_at1, W_at2, b_at2,
                                       W_at3, b_at3, out);
}